// Round 9
// baseline (653.320 us; speedup 1.0000x reference)
//
#include <hip/hip_runtime.h>
#include <cstdint>
#include <cstddef>

// ---------------------------------------------------------------------------
// CellGraphSAGE: 3x (SAGE-mean conv -> BN -> ReLU)
// dims: 128 -> 512 -> 256 -> 128, N=50000 nodes, E=800000 edges
// Round 9:
//  - XCD-sliced aggregation: column-slice the gather into 64B slices
//    (32 cols), slice = blockIdx % nsl so all blocks touching one slice land
//    on the same XCD (round-robin dispatch heuristic). Each XCD's 3.2 MB
//    slice stays L2-resident -> L2-miss traffic drops from 188 MB to
//    ~compulsory. 16-lane groups read exactly one 64B line per edge.
//  - rest unchanged from round 8 (bucket CSR, BK=64 glds GEMM, bf16 BN)
// ---------------------------------------------------------------------------

#define EPS_BN 1e-5f

typedef unsigned short ushort_t;
typedef __attribute__((ext_vector_type(8))) short short8;
typedef __attribute__((ext_vector_type(4))) float float4v;

__device__ __forceinline__ float bf2f(ushort_t u) {
    union { unsigned int i; float f; } v; v.i = ((unsigned int)u) << 16; return v.f;
}
__device__ __forceinline__ float bflo(unsigned int w) {
    union { unsigned int i; float f; } v; v.i = w << 16; return v.f;
}
__device__ __forceinline__ float bfhi(unsigned int w) {
    union { unsigned int i; float f; } v; v.i = w & 0xffff0000u; return v.f;
}
__device__ __forceinline__ ushort_t f2bf(float f) {
    union { float f; unsigned int i; } v; v.f = f;
    unsigned int r = v.i + 0x7fffu + ((v.i >> 16) & 1u);  // RNE
    return (ushort_t)(r >> 16);
}

// async 16B global -> LDS (wave-uniform base + lane*16)
__device__ __forceinline__ void async_copy16(void* lds, const void* g) {
    __builtin_amdgcn_global_load_lds(
        (const __attribute__((address_space(1))) unsigned int*)g,
        (__attribute__((address_space(3))) unsigned int*)lds, 16, 0, 0);
}

// ---------------- edge format hedge (int64 vs int32 storage) ---------------
__global__ void detect_fmt_kernel(const int* __restrict__ edges, int* __restrict__ nz) {
    int t = threadIdx.x;
    int cnt = 0;
    #pragma unroll
    for (int j = 0; j < 4; ++j) {
        int idx = 2 * (t * 4 + j) + 1;
        if (edges[idx] != 0) cnt++;
    }
    if (cnt) atomicAdd(nz, cnt);
}

__device__ __forceinline__ void edge_sd(const int* __restrict__ p, int e, int ne,
                                        bool is64, int& s, int& d) {
    if (is64) { s = p[2 * e];  d = p[2 * ne + 2 * e]; }
    else      { s = p[e];      d = p[ne + e]; }
}
__device__ __forceinline__ int edge_d(const int* __restrict__ p, int e, int ne, bool is64) {
    return is64 ? p[2 * ne + 2 * e] : p[ne + e];
}

// ---------------- bucket-sort CSR build ------------------------------------
// bucket b = dst >> 8 (256 nodes per bucket). packed entry = (dlow<<24) | src.
#define EPB 2048

__global__ __launch_bounds__(256) void bhist_kernel(
    const int* __restrict__ edges, int ne, const int* __restrict__ nz,
    int* __restrict__ gcnt) {
    __shared__ int h[256];
    int t = threadIdx.x;
    h[t] = 0;
    __syncthreads();
    bool is64 = (*nz == 0);
    int base_e = blockIdx.x * EPB;
    #pragma unroll
    for (int u = 0; u < EPB / 256; ++u) {
        int i = base_e + u * 256 + t;
        if (i < ne) atomicAdd(&h[edge_d(edges, i, ne, is64) >> 8], 1);
    }
    __syncthreads();
    if (h[t]) atomicAdd(&gcnt[t], h[t]);
}

__global__ __launch_bounds__(256) void bscan_kernel(
    const int* __restrict__ gcnt, int nb, int ne,
    int* __restrict__ bbase, int* __restrict__ bcur) {
    __shared__ int sh[256];
    int t = threadIdx.x;
    int v = (t < nb) ? gcnt[t] : 0;
    sh[t] = v;
    __syncthreads();
    for (int o = 1; o < 256; o <<= 1) {
        int x = (t >= o) ? sh[t - o] : 0;
        __syncthreads();
        sh[t] += x;
        __syncthreads();
    }
    int excl = sh[t] - v;
    if (t < nb) { bbase[t] = excl; bcur[t] = excl; }
    if (t == nb) bbase[t] = ne;
    if (t == 0 && nb == 256) bbase[256] = ne;
}

__global__ __launch_bounds__(256) void bscatter_kernel(
    const int* __restrict__ edges, int ne, const int* __restrict__ nz,
    int* __restrict__ bcur, int* __restrict__ packed) {
    __shared__ int h[256];
    __shared__ int chunkb[256];
    __shared__ int lcur[256];
    int t = threadIdx.x;
    h[t] = 0;
    lcur[t] = 0;
    __syncthreads();
    bool is64 = (*nz == 0);
    int base_e = blockIdx.x * EPB;
    int ent[EPB / 256], eb[EPB / 256];
    #pragma unroll
    for (int u = 0; u < EPB / 256; ++u) {
        int i = base_e + u * 256 + t;
        if (i < ne) {
            int s, d;
            edge_sd(edges, i, ne, is64, s, d);
            ent[u] = s | ((d & 255) << 24);
            eb[u] = d >> 8;
            atomicAdd(&h[eb[u]], 1);
        } else eb[u] = -1;
    }
    __syncthreads();
    if (h[t]) chunkb[t] = atomicAdd(&bcur[t], h[t]);
    __syncthreads();
    #pragma unroll
    for (int u = 0; u < EPB / 256; ++u) {
        if (eb[u] >= 0) {
            int lp = atomicAdd(&lcur[eb[u]], 1);
            packed[chunkb[eb[u]] + lp] = ent[u];
        }
    }
}

__global__ __launch_bounds__(256) void bbuild_kernel(
    const int* __restrict__ packed, const int* __restrict__ bbase,
    int* __restrict__ rowptr, int* __restrict__ csr_src, int n) {
    __shared__ int h[256];
    __shared__ int cur[256];
    int t = threadIdx.x;
    int bb = blockIdx.x;
    int base = bbase[bb], cnt = bbase[bb + 1] - base;
    h[t] = 0;
    __syncthreads();
    for (int i = t; i < cnt; i += 256)
        atomicAdd(&h[(unsigned)packed[base + i] >> 24], 1);
    __syncthreads();
    int v = h[t];
    for (int o = 1; o < 256; o <<= 1) {
        int x = (t >= o) ? h[t - o] : 0;
        __syncthreads();
        h[t] += x;
        __syncthreads();
    }
    int excl = h[t] - v;
    int node = bb * 256 + t;
    if (node <= n) rowptr[node] = base + excl;
    cur[t] = excl;
    __syncthreads();
    for (int i = t; i < cnt; i += 256) {
        int e = packed[base + i];
        int lp = atomicAdd(&cur[(unsigned)e >> 24], 1);
        csr_src[base + lp] = e & 0xffffff;
    }
}

// ---------------- conversions ----------------------------------------------
__global__ void f2b_kernel(const float* __restrict__ in, ushort_t* __restrict__ out, int n) {
    int i = blockIdx.x * 256 + threadIdx.x;
    if (i < n) out[i] = f2bf(in[i]);
}

__global__ void prep_wt_kernel(const float* __restrict__ Wl, const float* __restrict__ Wr,
                               ushort_t* __restrict__ WT, int K1, int Dout) {
    int idx = blockIdx.x * 256 + threadIdx.x;
    int K2 = 2 * K1;
    if (idx >= Dout * K2) return;
    int n = idx / K2, k = idx - n * K2;
    float v = (k < K1) ? Wl[(size_t)k * Dout + n] : Wr[(size_t)(k - K1) * Dout + n];
    WT[idx] = f2bf(v);
}

__global__ void prep_wtc_kernel(const float* __restrict__ Wl, const float* __restrict__ Wr,
                                ushort_t* __restrict__ WTc, int K, int D) {
    int idx = blockIdx.x * 256 + threadIdx.x;
    if (idx >= 2 * D * K) return;
    int nn = idx / K, k = idx - nn * K;
    float v = (nn < D) ? Wl[(size_t)k * D + nn] : Wr[(size_t)k * D + (nn - D)];
    WTc[idx] = f2bf(v);
}

// ---------------- XCD-sliced aggregation -----------------------------------
// Gather source rows sliced into 64B (16-uint) column slices; slice =
// blockIdx % nsl -> same-slice blocks land on one XCD (round-robin heuristic)
// and its 3.2 MB slice stays L2-resident. 16-lane group per node; one 64B
// line per edge per group.
// ADD: out[node] = mean(P[src]) + R[node] + bias   (PR layout, R at roff_u)
// !ADD: out[node] = mean(h[src])
template <bool ADD>
__global__ __launch_bounds__(256) void aggregate_sliced_kernel(
    const ushort_t* __restrict__ srcm, const float* __restrict__ bias,
    ushort_t* __restrict__ outb,
    const int* __restrict__ rowptr, const int* __restrict__ csr_src,
    int nnodes, int nsl, int rstride_u, int outw_u) {
    int slice = blockIdx.x % nsl;          // XCD-affine slice id
    int nb = blockIdx.x / nsl;
    int g = threadIdx.x >> 4;              // 16 groups of 16 lanes
    int lg = threadIdx.x & 15;
    int node = nb * 16 + g;
    if (node >= nnodes) return;
    int e0 = rowptr[node], e1 = rowptr[node + 1];

    const unsigned int* base = (const unsigned int*)srcm + (size_t)slice * 16 + lg;
    float a0 = 0.f, a1 = 0.f;
    int e = e0;
    for (; e + 8 <= e1; e += 8) {
        unsigned int w[8];
        #pragma unroll
        for (int u = 0; u < 8; ++u)
            w[u] = base[(size_t)csr_src[e + u] * rstride_u];
        #pragma unroll
        for (int u = 0; u < 8; ++u) { a0 += bflo(w[u]); a1 += bfhi(w[u]); }
    }
    if (e + 4 <= e1) {
        unsigned int w[4];
        #pragma unroll
        for (int u = 0; u < 4; ++u)
            w[u] = base[(size_t)csr_src[e + u] * rstride_u];
        #pragma unroll
        for (int u = 0; u < 4; ++u) { a0 += bflo(w[u]); a1 += bfhi(w[u]); }
        e += 4;
    }
    if (e + 2 <= e1) {
        unsigned int w0 = base[(size_t)csr_src[e] * rstride_u];
        unsigned int w1 = base[(size_t)csr_src[e + 1] * rstride_u];
        a0 += bflo(w0) + bflo(w1);
        a1 += bfhi(w0) + bfhi(w1);
        e += 2;
    }
    if (e < e1) {
        unsigned int w0 = base[(size_t)csr_src[e] * rstride_u];
        a0 += bflo(w0); a1 += bfhi(w0);
    }

    int deg = e1 - e0;
    float scale = 1.0f / (float)(deg > 1 ? deg : 1);
    float o0 = a0 * scale, o1 = a1 * scale;
    if (ADD) {
        unsigned int rw = ((const unsigned int*)srcm)
            [(size_t)node * rstride_u + outw_u + slice * 16 + lg];  // R half
        float2 bv = *(const float2*)(bias + slice * 32 + lg * 2);
        o0 += bflo(rw) + bv.x;
        o1 += bfhi(rw) + bv.y;
    }
    ((unsigned int*)outb)[(size_t)node * outw_u + slice * 16 + lg] =
        (unsigned int)f2bf(o0) | ((unsigned int)f2bf(o1) << 16);
}

// ---------------- MFMA GEMM, BK=64, global_load_lds + 3-bit swizzle --------
template <bool DUAL, bool BIAS>
__global__ __launch_bounds__(256) void gemm_glds_kernel(
    const ushort_t* __restrict__ A1, const ushort_t* __restrict__ A2,
    const ushort_t* __restrict__ BT, const float* __restrict__ bias,
    ushort_t* __restrict__ Cb, int N, int K1, int Ktot, int Wtot) {
    __shared__ ushort_t As[128 * 64];  // 16 KB
    __shared__ ushort_t Bs[128 * 64];  // 16 KB

    const int tid = threadIdx.x;
    const int wave = tid >> 6;
    const int lane = tid & 63;
    const int quad = lane >> 4;
    const int l15 = lane & 15;
    const int sw7 = l15 & 7;
    const int rowBase = blockIdx.y * 128;
    const int colBase = blockIdx.x * 128;
    const int wm = (wave >> 1) * 64;
    const int wn = (wave & 1) * 64;

    float4v acc[4][4];
    #pragma unroll
    for (int i = 0; i < 4; ++i)
        #pragma unroll
        for (int j = 0; j < 4; ++j)
            acc[i][j] = (float4v){0.f, 0.f, 0.f, 0.f};

    const int nkt = Ktot / 64;
    const int khalf = K1 / 64;

    for (int kt = 0; kt < nkt; ++kt) {
        const ushort_t* Asrc = A1;
        int kg = kt * 64;
        if (DUAL && kt >= khalf) { Asrc = A2; kg = (kt - khalf) * 64; }
        const int kb = kt * 64;

        #pragma unroll
        for (int u = 0; u < 4; ++u) {
            int c = u * 256 + tid;
            int r = c >> 3, cc = c & 7;
            int off = (cc ^ (r & 7)) * 8;
            int grow = rowBase + r;
            if (grow >= N) grow = N - 1;
            async_copy16(&As[c * 8], Asrc + (size_t)grow * K1 + kg + off);
            async_copy16(&Bs[c * 8], BT + (size_t)(colBase + r) * Ktot + kb + off);
        }
        __syncthreads();

        #pragma unroll
        for (int kh = 0; kh < 2; ++kh) {
            int cidx = kh * 4 + quad;
            short8 af[4], bf4[4];
            #pragma unroll
            for (int i = 0; i < 4; ++i)
                af[i] = *(const short8*)&As[(wm + i * 16 + l15) * 64 + (cidx ^ sw7) * 8];
            #pragma unroll
            for (int j = 0; j < 4; ++j)
                bf4[j] = *(const short8*)&Bs[(wn + j * 16 + l15) * 64 + (cidx ^ sw7) * 8];
            #pragma unroll
            for (int i = 0; i < 4; ++i)
                #pragma unroll
                for (int j = 0; j < 4; ++j)
                    acc[i][j] = __builtin_amdgcn_mfma_f32_16x16x32_bf16(bf4[j], af[i], acc[i][j], 0, 0, 0);
        }
        __syncthreads();
    }

    // epilogue: per-wave 4KB LDS restage -> full-line bf16 stores
    ushort_t* lws = &As[wave * 2048];
    #pragma unroll
    for (int p = 0; p < 2; ++p) {
        #pragma unroll
        for (int jj = 0; jj < 2; ++jj) {
            int j = 2 * p + jj;
            float4 bv = make_float4(0.f, 0.f, 0.f, 0.f);
            if (BIAS) bv = *(const float4*)(bias + colBase + wn + j * 16 + quad * 4);
            #pragma unroll
            for (int i = 0; i < 4; ++i) {
                uint2 pk;
                pk.x = (unsigned int)f2bf(acc[i][j][0] + bv.x) |
                       ((unsigned int)f2bf(acc[i][j][1] + bv.y) << 16);
                pk.y = (unsigned int)f2bf(acc[i][j][2] + bv.z) |
                       ((unsigned int)f2bf(acc[i][j][3] + bv.w) << 16);
                *(uint2*)&lws[(i * 16 + l15) * 32 + jj * 16 + quad * 4] = pk;
            }
        }
        __syncthreads();
        #pragma unroll
        for (int it = 0; it < 4; ++it) {
            int c = it * 64 + lane;
            int row = c >> 2, coff = (c & 3) * 8;
            int grow = rowBase + wm + row;
            if (grow < N) {
                uint4 v = *(const uint4*)&lws[row * 32 + coff];
                *(uint4*)(Cb + (size_t)grow * Wtot + colBase + wn + p * 32 + coff) = v;
            }
        }
        __syncthreads();
    }
}

// ---------------- BN stats (bf16 input) ------------------------------------
__global__ void colstats_b_kernel(const ushort_t* __restrict__ h, int N, int D,
                                  float* __restrict__ sum, float* __restrict__ sumsq) {
    int c2 = blockIdx.x * 128 + (threadIdx.x & 63) * 2;
    int rl = threadIdx.x >> 6;
    float s0 = 0.f, s20 = 0.f, s1 = 0.f, s21 = 0.f;
    int stride = gridDim.y * 4;
    for (int r = blockIdx.y * 4 + rl; r < N; r += stride) {
        unsigned int w = *(const unsigned int*)(h + (size_t)r * D + c2);
        float v0 = bflo(w), v1 = bfhi(w);
        s0 += v0; s20 += v0 * v0;
        s1 += v1; s21 += v1 * v1;
    }
    atomicAdd(&sum[c2 + 0], s0);
    atomicAdd(&sumsq[c2 + 0], s20);
    atomicAdd(&sum[c2 + 1], s1);
    atomicAdd(&sumsq[c2 + 1], s21);
}

// ---------------- BN apply (bf16 in) ---------------------------------------
__global__ void bn_relu_b2b_kernel(const ushort_t* __restrict__ h, ushort_t* __restrict__ hb,
                                   int N, int D,
                                   const float* __restrict__ sum, const float* __restrict__ sumsq,
                                   const float* __restrict__ g, const float* __restrict__ b) {
    size_t idx = (size_t)blockIdx.x * blockDim.x + threadIdx.x;
    size_t tot = (size_t)N * D / 2;
    if (idx >= tot) return;
    int cp = (int)(idx & (size_t)(D / 2 - 1));
    int c0 = cp * 2, c1 = c0 + 1;
    float m0 = sum[c0] / (float)N, m1 = sum[c1] / (float)N;
    float i0 = rsqrtf(sumsq[c0] / (float)N - m0 * m0 + EPS_BN);
    float i1 = rsqrtf(sumsq[c1] / (float)N - m1 * m1 + EPS_BN);
    unsigned int w = ((const unsigned int*)h)[idx];
    float v0 = g[c0] * (bflo(w) - m0) * i0 + b[c0];
    float v1 = g[c1] * (bfhi(w) - m1) * i1 + b[c1];
    v0 = v0 > 0.f ? v0 : 0.f;
    v1 = v1 > 0.f ? v1 : 0.f;
    ((unsigned int*)hb)[idx] = (unsigned int)f2bf(v0) | ((unsigned int)f2bf(v1) << 16);
}

__global__ void bn_relu_b2f_kernel(const ushort_t* __restrict__ h, float* __restrict__ hf,
                                   int N, int D,
                                   const float* __restrict__ sum, const float* __restrict__ sumsq,
                                   const float* __restrict__ g, const float* __restrict__ b) {
    size_t idx = (size_t)blockIdx.x * blockDim.x + threadIdx.x;
    size_t tot = (size_t)N * D / 2;
    if (idx >= tot) return;
    int cp = (int)(idx & (size_t)(D / 2 - 1));
    int c0 = cp * 2, c1 = c0 + 1;
    float m0 = sum[c0] / (float)N, m1 = sum[c1] / (float)N;
    float i0 = rsqrtf(sumsq[c0] / (float)N - m0 * m0 + EPS_BN);
    float i1 = rsqrtf(sumsq[c1] / (float)N - m1 * m1 + EPS_BN);
    unsigned int w = ((const unsigned int*)h)[idx];
    float v0 = g[c0] * (bflo(w) - m0) * i0 + b[c0];
    float v1 = g[c1] * (bfhi(w) - m1) * i1 + b[c1];
    float2 o;
    o.x = v0 > 0.f ? v0 : 0.f;
    o.y = v1 > 0.f ? v1 : 0.f;
    *(float2*)(hf + idx * 2) = o;
}

// ---------------------------------------------------------------------------
extern "C" void kernel_launch(void* const* d_in, const int* in_sizes, int n_in,
                              void* d_out, int out_size, void* d_ws, size_t ws_size,
                              hipStream_t stream) {
    const float* x     = (const float*)d_in[0];
    const int*   edges = (const int*)d_in[1];
    const float* Wl0 = (const float*)d_in[2];
    const float* bl0 = (const float*)d_in[3];
    const float* Wr0 = (const float*)d_in[4];
    const float* g0  = (const float*)d_in[5];
    const float* b0  = (const float*)d_in[6];
    const float* Wl1 = (const float*)d_in[7];
    const float* bl1 = (const float*)d_in[8];
    const float* Wr1 = (const float*)d_in[9];
    const float* g1  = (const float*)d_in[10];
    const float* b1  = (const float*)d_in[11];
    const float* Wl2 = (const float*)d_in[12];
    const float* bl2 = (const float*)d_in[13];
    const float* Wr2 = (const float*)d_in[14];
    const float* g2  = (const float*)d_in[15];
    const float* b2  = (const float*)d_in[16];

    const int D0 = 128, D1 = 512, D2 = 256, D3 = 128;
    const int n  = in_sizes[0] / D0;   // 50000
    const int ne = in_sizes[1] / 2;    // 800000
    const int NB = (n + 255) >> 8;     // 196 buckets

    // ---- workspace layout (zeroed block first -> one memset) ----
    char* base = (char*)d_ws;
    size_t off = 0;
    auto alloc = [&](size_t bytes) -> char* {
        char* p = base + off;
        off = (off + bytes + 255) & ~(size_t)255;
        return p;
    };
    int*      nzflag  = (int*)alloc(4);
    int*      gcnt    = (int*)alloc(256 * 4);
    float*    stats   = (float*)alloc(6 * 512 * 4);
    size_t    zero_span = off;
    int*      bbase   = (int*)alloc(257 * 4);
    int*      bcur    = (int*)alloc(256 * 4);
    int*      packed  = (int*)alloc((size_t)ne * 4);
    int*      rowptr  = (int*)alloc((size_t)(n + 1) * 4);
    int*      csr_src = (int*)alloc((size_t)ne * 4);
    ushort_t* xb      = (ushort_t*)alloc((size_t)n * D0 * 2);
    ushort_t* mb      = (ushort_t*)alloc((size_t)n * 512 * 2);   // mean(L0) / PR(L1,L2)
    ushort_t* h1b     = (ushort_t*)alloc((size_t)n * D1 * 2);
    ushort_t* h2b     = (ushort_t*)alloc((size_t)n * D2 * 2);
    ushort_t* hpre    = (ushort_t*)alloc((size_t)n * 512 * 2);   // bf16 pre-BN
    ushort_t* WT0     = (ushort_t*)alloc((size_t)D1 * 2 * D0 * 2);
    ushort_t* WT1c    = (ushort_t*)alloc((size_t)(2 * D2) * D1 * 2);
    ushort_t* WT2c    = (ushort_t*)alloc((size_t)(2 * D3) * D2 * 2);
    float*    out     = (float*)d_out;
    (void)ws_size; (void)n_in; (void)out_size;

    hipMemsetAsync(base, 0, zero_span, stream);

    // ---- edge format detection + bucket-sort CSR build ----
    detect_fmt_kernel<<<1, 256, 0, stream>>>(edges, nzflag);
    int ablk = (ne + EPB - 1) / EPB;
    bhist_kernel<<<ablk, 256, 0, stream>>>(edges, ne, nzflag, gcnt);
    bscan_kernel<<<1, 256, 0, stream>>>(gcnt, NB, ne, bbase, bcur);
    bscatter_kernel<<<ablk, 256, 0, stream>>>(edges, ne, nzflag, bcur, packed);
    bbuild_kernel<<<NB, 256, 0, stream>>>(packed, bbase, rowptr, csr_src, n);

    // ---- prep: x -> bf16, weights -> transposed bf16 ----
    f2b_kernel<<<((size_t)n * D0 + 255) / 256, 256, 0, stream>>>(x, xb, n * D0);
    prep_wt_kernel<<<(D1 * 2 * D0 + 255) / 256, 256, 0, stream>>>(Wl0, Wr0, WT0, D0, D1);
    prep_wtc_kernel<<<(2 * D2 * D1 + 255) / 256, 256, 0, stream>>>(Wl1, Wr1, WT1c, D1, D2);
    prep_wtc_kernel<<<(2 * D3 * D2 + 255) / 256, 256, 0, stream>>>(Wl2, Wr2, WT2c, D2, D3);

    const int rowBlocks = (n + 127) / 128;
    const int nodeBlocks = (n + 15) / 16;
    float* st0 = stats + 0 * 1024;
    float* st1 = stats + 1 * 1024;
    float* st2 = stats + 2 * 1024;

    // ---- layer 0: 128 -> 512 (aggregate-first: din < dout) ----
    aggregate_sliced_kernel<false><<<4 * nodeBlocks, 256, 0, stream>>>(
        xb, nullptr, mb, rowptr, csr_src, n, 4, D0 / 2, D0 / 2);
    gemm_glds_kernel<true, true><<<dim3(D1 / 128, rowBlocks), 256, 0, stream>>>(
        mb, xb, WT0, bl0, hpre, n, D0, 2 * D0, D1);
    colstats_b_kernel<<<dim3(D1 / 128, 128), 256, 0, stream>>>(hpre, n, D1, st0, st0 + 512);
    bn_relu_b2b_kernel<<<((size_t)n * D1 / 2 + 255) / 256, 256, 0, stream>>>(
        hpre, h1b, n, D1, st0, st0 + 512, g0, b0);

    // ---- layer 1: 512 -> 256 (project-first, fused [P|R]) ----
    gemm_glds_kernel<false, false><<<dim3(2 * D2 / 128, rowBlocks), 256, 0, stream>>>(
        h1b, nullptr, WT1c, nullptr, mb, n, D1, D1, 2 * D2);      // PR1 = h1 @ [Wl1|Wr1]
    aggregate_sliced_kernel<true><<<8 * nodeBlocks, 256, 0, stream>>>(
        mb, bl1, hpre, rowptr, csr_src, n, 8, D2, D2 / 2);        // pre = mean(P)+R+bl1
    colstats_b_kernel<<<dim3(D2 / 128, 128), 256, 0, stream>>>(hpre, n, D2, st1, st1 + 512);
    bn_relu_b2b_kernel<<<((size_t)n * D2 / 2 + 255) / 256, 256, 0, stream>>>(
        hpre, h2b, n, D2, st1, st1 + 512, g1, b1);

    // ---- layer 2: 256 -> 128 (project-first, fused [P|R]) ----
    gemm_glds_kernel<false, false><<<dim3(2 * D3 / 128, rowBlocks), 256, 0, stream>>>(
        h2b, nullptr, WT2c, nullptr, mb, n, D2, D2, 2 * D3);      // PR2 = h2 @ [Wl2|Wr2]
    aggregate_sliced_kernel<true><<<4 * nodeBlocks, 256, 0, stream>>>(
        mb, bl2, hpre, rowptr, csr_src, n, 4, D3, D3 / 2);        // pre = mean(P)+R+bl2
    colstats_b_kernel<<<dim3(D3 / 128, 128), 256, 0, stream>>>(hpre, n, D3, st2, st2 + 512);
    bn_relu_b2f_kernel<<<((size_t)n * D3 / 2 + 255) / 256, 256, 0, stream>>>(
        hpre, out, n, D3, st2, st2 + 512, g2, b2);
}

// Round 10
// 623.377 us; speedup vs baseline: 1.0480x; 1.0480x over previous
//
#include <hip/hip_runtime.h>
#include <cstdint>
#include <cstddef>

// ---------------------------------------------------------------------------
// CellGraphSAGE: 3x (SAGE-mean conv -> BN -> ReLU)
// dims: 128 -> 512 -> 256 -> 128, N=50000 nodes, E=800000 edges
// Round 10:
//  - REVERT round-9 XCD slicing (mapping heuristic failed; FETCH went UP).
//    Back to round-8 wave-per-node gather.
//  - L0 colstats fused into the GEMM epilogue (shfl_xor col-reduce + atomics;
//    col is l15-invariant in the swapped C layout) -> 51 MB pass removed.
//  - prep kernels (f2b + 3 weight transposes) merged into one dispatch.
// ---------------------------------------------------------------------------

#define EPS_BN 1e-5f

typedef unsigned short ushort_t;
typedef __attribute__((ext_vector_type(8))) short short8;
typedef __attribute__((ext_vector_type(4))) float float4v;

__device__ __forceinline__ float bf2f(ushort_t u) {
    union { unsigned int i; float f; } v; v.i = ((unsigned int)u) << 16; return v.f;
}
__device__ __forceinline__ float bflo(unsigned int w) {
    union { unsigned int i; float f; } v; v.i = w << 16; return v.f;
}
__device__ __forceinline__ float bfhi(unsigned int w) {
    union { unsigned int i; float f; } v; v.i = w & 0xffff0000u; return v.f;
}
__device__ __forceinline__ ushort_t f2bf(float f) {
    union { float f; unsigned int i; } v; v.f = f;
    unsigned int r = v.i + 0x7fffu + ((v.i >> 16) & 1u);  // RNE
    return (ushort_t)(r >> 16);
}

// async 16B global -> LDS (wave-uniform base + lane*16)
__device__ __forceinline__ void async_copy16(void* lds, const void* g) {
    __builtin_amdgcn_global_load_lds(
        (const __attribute__((address_space(1))) unsigned int*)g,
        (__attribute__((address_space(3))) unsigned int*)lds, 16, 0, 0);
}

// ---------------- edge format hedge (int64 vs int32 storage) ---------------
__global__ void detect_fmt_kernel(const int* __restrict__ edges, int* __restrict__ nz) {
    int t = threadIdx.x;
    int cnt = 0;
    #pragma unroll
    for (int j = 0; j < 4; ++j) {
        int idx = 2 * (t * 4 + j) + 1;
        if (edges[idx] != 0) cnt++;
    }
    if (cnt) atomicAdd(nz, cnt);
}

__device__ __forceinline__ void edge_sd(const int* __restrict__ p, int e, int ne,
                                        bool is64, int& s, int& d) {
    if (is64) { s = p[2 * e];  d = p[2 * ne + 2 * e]; }
    else      { s = p[e];      d = p[ne + e]; }
}
__device__ __forceinline__ int edge_d(const int* __restrict__ p, int e, int ne, bool is64) {
    return is64 ? p[2 * ne + 2 * e] : p[ne + e];
}

// ---------------- bucket-sort CSR build ------------------------------------
#define EPB 2048

__global__ __launch_bounds__(256) void bhist_kernel(
    const int* __restrict__ edges, int ne, const int* __restrict__ nz,
    int* __restrict__ gcnt) {
    __shared__ int h[256];
    int t = threadIdx.x;
    h[t] = 0;
    __syncthreads();
    bool is64 = (*nz == 0);
    int base_e = blockIdx.x * EPB;
    #pragma unroll
    for (int u = 0; u < EPB / 256; ++u) {
        int i = base_e + u * 256 + t;
        if (i < ne) atomicAdd(&h[edge_d(edges, i, ne, is64) >> 8], 1);
    }
    __syncthreads();
    if (h[t]) atomicAdd(&gcnt[t], h[t]);
}

__global__ __launch_bounds__(256) void bscan_kernel(
    const int* __restrict__ gcnt, int nb, int ne,
    int* __restrict__ bbase, int* __restrict__ bcur) {
    __shared__ int sh[256];
    int t = threadIdx.x;
    int v = (t < nb) ? gcnt[t] : 0;
    sh[t] = v;
    __syncthreads();
    for (int o = 1; o < 256; o <<= 1) {
        int x = (t >= o) ? sh[t - o] : 0;
        __syncthreads();
        sh[t] += x;
        __syncthreads();
    }
    int excl = sh[t] - v;
    if (t < nb) { bbase[t] = excl; bcur[t] = excl; }
    if (t == nb) bbase[t] = ne;
    if (t == 0 && nb == 256) bbase[256] = ne;
}

__global__ __launch_bounds__(256) void bscatter_kernel(
    const int* __restrict__ edges, int ne, const int* __restrict__ nz,
    int* __restrict__ bcur, int* __restrict__ packed) {
    __shared__ int h[256];
    __shared__ int chunkb[256];
    __shared__ int lcur[256];
    int t = threadIdx.x;
    h[t] = 0;
    lcur[t] = 0;
    __syncthreads();
    bool is64 = (*nz == 0);
    int base_e = blockIdx.x * EPB;
    int ent[EPB / 256], eb[EPB / 256];
    #pragma unroll
    for (int u = 0; u < EPB / 256; ++u) {
        int i = base_e + u * 256 + t;
        if (i < ne) {
            int s, d;
            edge_sd(edges, i, ne, is64, s, d);
            ent[u] = s | ((d & 255) << 24);
            eb[u] = d >> 8;
            atomicAdd(&h[eb[u]], 1);
        } else eb[u] = -1;
    }
    __syncthreads();
    if (h[t]) chunkb[t] = atomicAdd(&bcur[t], h[t]);
    __syncthreads();
    #pragma unroll
    for (int u = 0; u < EPB / 256; ++u) {
        if (eb[u] >= 0) {
            int lp = atomicAdd(&lcur[eb[u]], 1);
            packed[chunkb[eb[u]] + lp] = ent[u];
        }
    }
}

__global__ __launch_bounds__(256) void bbuild_kernel(
    const int* __restrict__ packed, const int* __restrict__ bbase,
    int* __restrict__ rowptr, int* __restrict__ csr_src, int n) {
    __shared__ int h[256];
    __shared__ int cur[256];
    int t = threadIdx.x;
    int bb = blockIdx.x;
    int base = bbase[bb], cnt = bbase[bb + 1] - base;
    h[t] = 0;
    __syncthreads();
    for (int i = t; i < cnt; i += 256)
        atomicAdd(&h[(unsigned)packed[base + i] >> 24], 1);
    __syncthreads();
    int v = h[t];
    for (int o = 1; o < 256; o <<= 1) {
        int x = (t >= o) ? h[t - o] : 0;
        __syncthreads();
        h[t] += x;
        __syncthreads();
    }
    int excl = h[t] - v;
    int node = bb * 256 + t;
    if (node <= n) rowptr[node] = base + excl;
    cur[t] = excl;
    __syncthreads();
    for (int i = t; i < cnt; i += 256) {
        int e = packed[base + i];
        int lp = atomicAdd(&cur[(unsigned)e >> 24], 1);
        csr_src[base + lp] = e & 0xffffff;
    }
}

// ---------------- merged prep: x->bf16 + 3 transposed weight preps ---------
__global__ void prep_all_kernel(
    const float* __restrict__ x, ushort_t* __restrict__ xb, int nxb,
    const float* __restrict__ Wl0, const float* __restrict__ Wr0,
    ushort_t* __restrict__ WT0, int nb0,   // WT0: D1 x 2*D0 (K-concat), K1=128,Dout=512
    const float* __restrict__ Wl1, const float* __restrict__ Wr1,
    ushort_t* __restrict__ WT1c, int nb1,  // WT1c: (2*D2) x D1
    const float* __restrict__ Wl2, const float* __restrict__ Wr2,
    ushort_t* __restrict__ WT2c) {         // WT2c: (2*D3) x D2
    const int D0 = 128, D1 = 512, D2 = 256, D3 = 128;
    int b = blockIdx.x;
    if (b < nxb) {
        int i = b * 256 + threadIdx.x;
        xb[i] = f2bf(x[i]);
        return;
    }
    b -= nxb;
    if (b < nb0) {
        int idx = b * 256 + threadIdx.x;       // over D1 * 2*D0
        int K2 = 2 * D0;
        int nn = idx / K2, k = idx - nn * K2;
        float v = (k < D0) ? Wl0[(size_t)k * D1 + nn] : Wr0[(size_t)(k - D0) * D1 + nn];
        WT0[idx] = f2bf(v);
        return;
    }
    b -= nb0;
    if (b < nb1) {
        int idx = b * 256 + threadIdx.x;       // over 2*D2 * D1
        int nn = idx / D1, k = idx - nn * D1;
        float v = (nn < D2) ? Wl1[(size_t)k * D2 + nn] : Wr1[(size_t)k * D2 + (nn - D2)];
        WT1c[idx] = f2bf(v);
        return;
    }
    b -= nb1;
    {
        int idx = b * 256 + threadIdx.x;       // over 2*D3 * D2
        int nn = idx / D2, k = idx - nn * D2;
        float v = (nn < D3) ? Wl2[(size_t)k * D3 + nn] : Wr2[(size_t)k * D3 + (nn - D3)];
        WT2c[idx] = f2bf(v);
    }
}

// ---------------- aggregation helpers --------------------------------------
template <int VEC> struct VecT;
template <> struct VecT<2> { using T = unsigned int; };
template <> struct VecT<4> { using T = uint2; };
template <> struct VecT<8> { using T = uint4; };

template <int VEC>
__device__ __forceinline__ void vunpack(typename VecT<VEC>::T v, unsigned int* w) {
    if constexpr (VEC == 2) { w[0] = v; }
    else if constexpr (VEC == 4) { w[0] = v.x; w[1] = v.y; }
    else { w[0] = v.x; w[1] = v.y; w[2] = v.z; w[3] = v.w; }
}

template <int VEC>
__device__ __forceinline__ void vaccum(typename VecT<VEC>::T v, float* acc) {
    unsigned int w[VEC / 2];
    vunpack<VEC>(v, w);
    #pragma unroll
    for (int i = 0; i < VEC / 2; ++i) {
        acc[2 * i + 0] += bflo(w[i]);
        acc[2 * i + 1] += bfhi(w[i]);
    }
}

template <int VEC>
__device__ __forceinline__ void gather_sum(
    const ushort_t* __restrict__ base, const int* __restrict__ csr_src,
    int e0, int e1, int rstride, float* acc) {
    using VT = typename VecT<VEC>::T;
    int e = e0;
    for (; e + 8 <= e1; e += 8) {
        VT v[8];
        #pragma unroll
        for (int u = 0; u < 8; ++u)
            v[u] = *(const VT*)(base + (size_t)csr_src[e + u] * rstride);
        #pragma unroll
        for (int u = 0; u < 8; ++u) vaccum<VEC>(v[u], acc);
    }
    if (e + 4 <= e1) {
        VT v[4];
        #pragma unroll
        for (int u = 0; u < 4; ++u)
            v[u] = *(const VT*)(base + (size_t)csr_src[e + u] * rstride);
        #pragma unroll
        for (int u = 0; u < 4; ++u) vaccum<VEC>(v[u], acc);
        e += 4;
    }
    if (e + 2 <= e1) {
        VT v0 = *(const VT*)(base + (size_t)csr_src[e] * rstride);
        VT v1 = *(const VT*)(base + (size_t)csr_src[e + 1] * rstride);
        vaccum<VEC>(v0, acc); vaccum<VEC>(v1, acc);
        e += 2;
    }
    if (e < e1)
        vaccum<VEC>(*(const VT*)(base + (size_t)csr_src[e] * rstride), acc);
}

// ---------------- plain aggregation (layer 0): bf16 mean -------------------
template <int VEC>
__global__ __launch_bounds__(256) void aggregate_wave_kernel(
    const ushort_t* __restrict__ h, ushort_t* __restrict__ mean,
    const int* __restrict__ rowptr, const int* __restrict__ csr_src, int nnodes) {
    const int din = VEC * 64;
    int wid = blockIdx.x * 4 + (threadIdx.x >> 6);
    if (wid >= nnodes) return;
    int lane = threadIdx.x & 63;
    int e0 = rowptr[wid], e1 = rowptr[wid + 1];

    float acc[VEC];
    #pragma unroll
    for (int i = 0; i < VEC; ++i) acc[i] = 0.f;
    gather_sum<VEC>(h + (size_t)lane * VEC, csr_src, e0, e1, din, acc);

    int deg = e1 - e0;
    float scale = 1.0f / (float)(deg > 1 ? deg : 1);
    unsigned int o[VEC / 2];
    #pragma unroll
    for (int i = 0; i < VEC / 2; ++i)
        o[i] = (unsigned int)f2bf(acc[2 * i] * scale) |
               ((unsigned int)f2bf(acc[2 * i + 1] * scale) << 16);
    using VT = typename VecT<VEC>::T;
    VT ov;
    if constexpr (VEC == 2) { ov = o[0]; }
    else if constexpr (VEC == 4) { ov.x = o[0]; ov.y = o[1]; }
    else { ov.x = o[0]; ov.y = o[1]; ov.z = o[2]; ov.w = o[3]; }
    *(VT*)(mean + (size_t)wid * din + (size_t)lane * VEC) = ov;
}

// ---------------- fused aggregate + add, bf16 out (layers 1/2) -------------
template <int VEC>  // VEC = D/64
__global__ __launch_bounds__(256) void aggregate_add_kernel(
    const ushort_t* __restrict__ PR, const float* __restrict__ bias,
    ushort_t* __restrict__ pre,
    const int* __restrict__ rowptr, const int* __restrict__ csr_src, int nnodes) {
    const int D = VEC * 64;
    const int stride = 2 * D;
    int wid = blockIdx.x * 4 + (threadIdx.x >> 6);
    if (wid >= nnodes) return;
    int lane = threadIdx.x & 63;
    int e0 = rowptr[wid], e1 = rowptr[wid + 1];

    float acc[VEC];
    #pragma unroll
    for (int i = 0; i < VEC; ++i) acc[i] = 0.f;
    gather_sum<VEC>(PR + (size_t)lane * VEC, csr_src, e0, e1, stride, acc);

    int deg = e1 - e0;
    float scale = 1.0f / (float)(deg > 1 ? deg : 1);

    using VT = typename VecT<VEC>::T;
    VT rv = *(const VT*)(PR + (size_t)wid * stride + D + (size_t)lane * VEC);
    unsigned int rw[VEC / 2];
    vunpack<VEC>(rv, rw);
    float o[VEC];
    #pragma unroll
    for (int i = 0; i < VEC / 2; ++i) {
        o[2 * i + 0] = bflo(rw[i]);
        o[2 * i + 1] = bfhi(rw[i]);
    }
    #pragma unroll
    for (int i = 0; i < VEC; ++i)
        o[i] += acc[i] * scale + bias[lane * VEC + i];

    unsigned int ow[VEC / 2];
    #pragma unroll
    for (int i = 0; i < VEC / 2; ++i)
        ow[i] = (unsigned int)f2bf(o[2 * i]) | ((unsigned int)f2bf(o[2 * i + 1]) << 16);
    VT ov;
    if constexpr (VEC == 2) { ov = ow[0]; }
    else if constexpr (VEC == 4) { ov.x = ow[0]; ov.y = ow[1]; }
    else { ov.x = ow[0]; ov.y = ow[1]; ov.z = ow[2]; ov.w = ow[3]; }
    *(VT*)(pre + (size_t)wid * D + (size_t)lane * VEC) = ov;
}

// ---------------- MFMA GEMM, BK=64, glds + swizzle + fused colstats --------
// DUAL: C = [A1|A2] @ BT^T ; BIAS adds bias[col]; STATS: atomicAdd column
// sum/sumsq of the (biased, fp32) outputs, rows masked to < N.
template <bool DUAL, bool BIAS, bool STATS>
__global__ __launch_bounds__(256) void gemm_glds_kernel(
    const ushort_t* __restrict__ A1, const ushort_t* __restrict__ A2,
    const ushort_t* __restrict__ BT, const float* __restrict__ bias,
    ushort_t* __restrict__ Cb, float* __restrict__ sum, float* __restrict__ sumsq,
    int N, int K1, int Ktot, int Wtot) {
    __shared__ ushort_t As[128 * 64];  // 16 KB
    __shared__ ushort_t Bs[128 * 64];  // 16 KB

    const int tid = threadIdx.x;
    const int wave = tid >> 6;
    const int lane = tid & 63;
    const int quad = lane >> 4;
    const int l15 = lane & 15;
    const int sw7 = l15 & 7;
    const int rowBase = blockIdx.y * 128;
    const int colBase = blockIdx.x * 128;
    const int wm = (wave >> 1) * 64;
    const int wn = (wave & 1) * 64;

    float4v acc[4][4];
    #pragma unroll
    for (int i = 0; i < 4; ++i)
        #pragma unroll
        for (int j = 0; j < 4; ++j)
            acc[i][j] = (float4v){0.f, 0.f, 0.f, 0.f};

    const int nkt = Ktot / 64;
    const int khalf = K1 / 64;

    for (int kt = 0; kt < nkt; ++kt) {
        const ushort_t* Asrc = A1;
        int kg = kt * 64;
        if (DUAL && kt >= khalf) { Asrc = A2; kg = (kt - khalf) * 64; }
        const int kb = kt * 64;

        #pragma unroll
        for (int u = 0; u < 4; ++u) {
            int c = u * 256 + tid;
            int r = c >> 3, cc = c & 7;
            int off = (cc ^ (r & 7)) * 8;
            int grow = rowBase + r;
            if (grow >= N) grow = N - 1;
            async_copy16(&As[c * 8], Asrc + (size_t)grow * K1 + kg + off);
            async_copy16(&Bs[c * 8], BT + (size_t)(colBase + r) * Ktot + kb + off);
        }
        __syncthreads();

        #pragma unroll
        for (int kh = 0; kh < 2; ++kh) {
            int cidx = kh * 4 + quad;
            short8 af[4], bf4[4];
            #pragma unroll
            for (int i = 0; i < 4; ++i)
                af[i] = *(const short8*)&As[(wm + i * 16 + l15) * 64 + (cidx ^ sw7) * 8];
            #pragma unroll
            for (int j = 0; j < 4; ++j)
                bf4[j] = *(const short8*)&Bs[(wn + j * 16 + l15) * 64 + (cidx ^ sw7) * 8];
            #pragma unroll
            for (int i = 0; i < 4; ++i)
                #pragma unroll
                for (int j = 0; j < 4; ++j)
                    acc[i][j] = __builtin_amdgcn_mfma_f32_16x16x32_bf16(bf4[j], af[i], acc[i][j], 0, 0, 0);
        }
        __syncthreads();
    }

    // bias into acc (so stats + packing see final values)
    if (BIAS) {
        #pragma unroll
        for (int j = 0; j < 4; ++j) {
            float4 bv = *(const float4*)(bias + colBase + wn + j * 16 + quad * 4);
            #pragma unroll
            for (int i = 0; i < 4; ++i) {
                acc[i][j][0] += bv.x; acc[i][j][1] += bv.y;
                acc[i][j][2] += bv.z; acc[i][j][3] += bv.w;
            }
        }
    }

    // fused colstats: col = colBase+wn+j*16+quad*4+r is l15-invariant
    if (STATS) {
        #pragma unroll
        for (int j = 0; j < 4; ++j) {
            #pragma unroll
            for (int r = 0; r < 4; ++r) {
                float s = 0.f, s2 = 0.f;
                #pragma unroll
                for (int i = 0; i < 4; ++i) {
                    int row = rowBase + wm + i * 16 + l15;
                    float v = (row < N) ? acc[i][j][r] : 0.f;
                    s += v; s2 += v * v;
                }
                #pragma unroll
                for (int m = 1; m < 16; m <<= 1) {
                    s  += __shfl_xor(s, m, 64);
                    s2 += __shfl_xor(s2, m, 64);
                }
                if (l15 == 0) {
                    int col = colBase + wn + j * 16 + quad * 4 + r;
                    atomicAdd(&sum[col], s);
                    atomicAdd(&sumsq[col], s2);
                }
            }
        }
    }

    // epilogue: per-wave 4KB LDS restage -> full-line bf16 stores
    ushort_t* lws = &As[wave * 2048];
    #pragma unroll
    for (int p = 0; p < 2; ++p) {
        #pragma unroll
        for (int jj = 0; jj < 2; ++jj) {
            int j = 2 * p + jj;
            #pragma unroll
            for (int i = 0; i < 4; ++i) {
                uint2 pk;
                pk.x = (unsigned int)f2bf(acc[i][j][0]) |
                       ((unsigned int)f2bf(acc[i][j][1]) << 16);
                pk.y = (unsigned int)f2bf(acc[i][j][2]) |
                       ((unsigned int)f2bf(acc[i][j][3]) << 16);
                *(uint2*)&lws[(i * 16 + l15) * 32 + jj * 16 + quad * 4] = pk;
            }
        }
        __syncthreads();
        #pragma unroll
        for (int it = 0; it < 4; ++it) {
            int c = it * 64 + lane;
            int row = c >> 2, coff = (c & 3) * 8;
            int grow = rowBase + wm + row;
            if (grow < N) {
                uint4 v = *(const uint4*)&lws[row * 32 + coff];
                *(uint4*)(Cb + (size_t)grow * Wtot + colBase + wn + p * 32 + coff) = v;
            }
        }
        __syncthreads();
    }
}

// ---------------- BN stats (bf16 input; layers 1/2) ------------------------
__global__ void colstats_b_kernel(const ushort_t* __restrict__ h, int N, int D,
                                  float* __restrict__ sum, float* __restrict__ sumsq) {
    int c2 = blockIdx.x * 128 + (threadIdx.x & 63) * 2;
    int rl = threadIdx.x >> 6;
    float s0 = 0.f, s20 = 0.f, s1 = 0.f, s21 = 0.f;
    int stride = gridDim.y * 4;
    for (int r = blockIdx.y * 4 + rl; r < N; r += stride) {
        unsigned int w = *(const unsigned int*)(h + (size_t)r * D + c2);
        float v0 = bflo(w), v1 = bfhi(w);
        s0 += v0; s20 += v0 * v0;
        s1 += v1; s21 += v1 * v1;
    }
    atomicAdd(&sum[c2 + 0], s0);
    atomicAdd(&sumsq[c2 + 0], s20);
    atomicAdd(&sum[c2 + 1], s1);
    atomicAdd(&sumsq[c2 + 1], s21);
}

// ---------------- BN apply (bf16 in) ---------------------------------------
__global__ void bn_relu_b2b_kernel(const ushort_t* __restrict__ h, ushort_t* __restrict__ hb,
                                   int N, int D,
                                   const float* __restrict__ sum, const float* __restrict__ sumsq,
                                   const float* __restrict__ g, const float* __restrict__ b) {
    size_t idx = (size_t)blockIdx.x * blockDim.x + threadIdx.x;
    size_t tot = (size_t)N * D / 2;
    if (idx >= tot) return;
    int cp = (int)(idx & (size_t)(D / 2 - 1));
    int c0 = cp * 2, c1 = c0 + 1;
    float m0 = sum[c0] / (float)N, m1 = sum[c1] / (float)N;
    float i0 = rsqrtf(sumsq[c0] / (float)N - m0 * m0 + EPS_BN);
    float i1 = rsqrtf(sumsq[c1] / (float)N - m1 * m1 + EPS_BN);
    unsigned int w = ((const unsigned int*)h)[idx];
    float v0 = g[c0] * (bflo(w) - m0) * i0 + b[c0];
    float v1 = g[c1] * (bfhi(w) - m1) * i1 + b[c1];
    v0 = v0 > 0.f ? v0 : 0.f;
    v1 = v1 > 0.f ? v1 : 0.f;
    ((unsigned int*)hb)[idx] = (unsigned int)f2bf(v0) | ((unsigned int)f2bf(v1) << 16);
}

__global__ void bn_relu_b2f_kernel(const ushort_t* __restrict__ h, float* __restrict__ hf,
                                   int N, int D,
                                   const float* __restrict__ sum, const float* __restrict__ sumsq,
                                   const float* __restrict__ g, const float* __restrict__ b) {
    size_t idx = (size_t)blockIdx.x * blockDim.x + threadIdx.x;
    size_t tot = (size_t)N * D / 2;
    if (idx >= tot) return;
    int cp = (int)(idx & (size_t)(D / 2 - 1));
    int c0 = cp * 2, c1 = c0 + 1;
    float m0 = sum[c0] / (float)N, m1 = sum[c1] / (float)N;
    float i0 = rsqrtf(sumsq[c0] / (float)N - m0 * m0 + EPS_BN);
    float i1 = rsqrtf(sumsq[c1] / (float)N - m1 * m1 + EPS_BN);
    unsigned int w = ((const unsigned int*)h)[idx];
    float v0 = g[c0] * (bflo(w) - m0) * i0 + b[c0];
    float v1 = g[c1] * (bfhi(w) - m1) * i1 + b[c1];
    float2 o;
    o.x = v0 > 0.f ? v0 : 0.f;
    o.y = v1 > 0.f ? v1 : 0.f;
    *(float2*)(hf + idx * 2) = o;
}

// ---------------------------------------------------------------------------
extern "C" void kernel_launch(void* const* d_in, const int* in_sizes, int n_in,
                              void* d_out, int out_size, void* d_ws, size_t ws_size,
                              hipStream_t stream) {
    const float* x     = (const float*)d_in[0];
    const int*   edges = (const int*)d_in[1];
    const float* Wl0 = (const float*)d_in[2];
    const float* bl0 = (const float*)d_in[3];
    const float* Wr0 = (const float*)d_in[4];
    const float* g0  = (const float*)d_in[5];
    const float* b0  = (const float*)d_in[6];
    const float* Wl1 = (const float*)d_in[7];
    const float* bl1 = (const float*)d_in[8];
    const float* Wr1 = (const float*)d_in[9];
    const float* g1  = (const float*)d_in[10];
    const float* b1  = (const float*)d_in[11];
    const float* Wl2 = (const float*)d_in[12];
    const float* bl2 = (const float*)d_in[13];
    const float* Wr2 = (const float*)d_in[14];
    const float* g2  = (const float*)d_in[15];
    const float* b2  = (const float*)d_in[16];

    const int D0 = 128, D1 = 512, D2 = 256, D3 = 128;
    const int n  = in_sizes[0] / D0;   // 50000
    const int ne = in_sizes[1] / 2;    // 800000
    const int NB = (n + 255) >> 8;     // 196 buckets

    // ---- workspace layout (zeroed block first -> one memset) ----
    char* base = (char*)d_ws;
    size_t off = 0;
    auto alloc = [&](size_t bytes) -> char* {
        char* p = base + off;
        off = (off + bytes + 255) & ~(size_t)255;
        return p;
    };
    int*      nzflag  = (int*)alloc(4);
    int*      gcnt    = (int*)alloc(256 * 4);
    float*    stats   = (float*)alloc(6 * 512 * 4);
    size_t    zero_span = off;
    int*      bbase   = (int*)alloc(257 * 4);
    int*      bcur    = (int*)alloc(256 * 4);
    int*      packed  = (int*)alloc((size_t)ne * 4);
    int*      rowptr  = (int*)alloc((size_t)(n + 1) * 4);
    int*      csr_src = (int*)alloc((size_t)ne * 4);
    ushort_t* xb      = (ushort_t*)alloc((size_t)n * D0 * 2);
    ushort_t* mb      = (ushort_t*)alloc((size_t)n * 512 * 2);   // mean(L0) / PR(L1,L2)
    ushort_t* h1b     = (ushort_t*)alloc((size_t)n * D1 * 2);
    ushort_t* h2b     = (ushort_t*)alloc((size_t)n * D2 * 2);
    ushort_t* hpre    = (ushort_t*)alloc((size_t)n * 512 * 2);   // bf16 pre-BN
    ushort_t* WT0     = (ushort_t*)alloc((size_t)D1 * 2 * D0 * 2);
    ushort_t* WT1c    = (ushort_t*)alloc((size_t)(2 * D2) * D1 * 2);
    ushort_t* WT2c    = (ushort_t*)alloc((size_t)(2 * D3) * D2 * 2);
    float*    out     = (float*)d_out;
    (void)ws_size; (void)n_in; (void)out_size;

    hipMemsetAsync(base, 0, zero_span, stream);

    // ---- edge format detection + bucket-sort CSR build ----
    detect_fmt_kernel<<<1, 256, 0, stream>>>(edges, nzflag);
    int ablk = (ne + EPB - 1) / EPB;
    bhist_kernel<<<ablk, 256, 0, stream>>>(edges, ne, nzflag, gcnt);
    bscan_kernel<<<1, 256, 0, stream>>>(gcnt, NB, ne, bbase, bcur);
    bscatter_kernel<<<ablk, 256, 0, stream>>>(edges, ne, nzflag, bcur, packed);
    bbuild_kernel<<<NB, 256, 0, stream>>>(packed, bbase, rowptr, csr_src, n);

    // ---- merged prep (x->bf16 + all weight transposes) ----
    const int nxb = (n * D0) / 256;               // 25000
    const int nb0 = (D1 * 2 * D0) / 256;          // 512
    const int nb1 = (2 * D2 * D1) / 256;          // 1024
    const int nb2 = (2 * D3 * D2) / 256;          // 256
    prep_all_kernel<<<nxb + nb0 + nb1 + nb2, 256, 0, stream>>>(
        x, xb, nxb, Wl0, Wr0, WT0, nb0, Wl1, Wr1, WT1c, nb1, Wl2, Wr2, WT2c);

    const int aggGrid = (n + 3) / 4;
    const int rowBlocks = (n + 127) / 128;
    float* st0 = stats + 0 * 1024;
    float* st1 = stats + 1 * 1024;
    float* st2 = stats + 2 * 1024;

    // ---- layer 0: 128 -> 512 (aggregate-first; colstats fused in GEMM) ----
    aggregate_wave_kernel<2><<<aggGrid, 256, 0, stream>>>(xb, mb, rowptr, csr_src, n);
    gemm_glds_kernel<true, true, true><<<dim3(D1 / 128, rowBlocks), 256, 0, stream>>>(
        mb, xb, WT0, bl0, hpre, st0, st0 + 512, n, D0, 2 * D0, D1);
    bn_relu_b2b_kernel<<<((size_t)n * D1 / 2 + 255) / 256, 256, 0, stream>>>(
        hpre, h1b, n, D1, st0, st0 + 512, g0, b0);

    // ---- layer 1: 512 -> 256 (project-first, fused [P|R]) ----
    gemm_glds_kernel<false, false, false><<<dim3(2 * D2 / 128, rowBlocks), 256, 0, stream>>>(
        h1b, nullptr, WT1c, nullptr, mb, nullptr, nullptr, n, D1, D1, 2 * D2);
    aggregate_add_kernel<4><<<aggGrid, 256, 0, stream>>>(
        mb, bl1, hpre, rowptr, csr_src, n);                        // pre = mean(P)+R+bl1
    colstats_b_kernel<<<dim3(D2 / 128, 128), 256, 0, stream>>>(hpre, n, D2, st1, st1 + 512);
    bn_relu_b2b_kernel<<<((size_t)n * D2 / 2 + 255) / 256, 256, 0, stream>>>(
        hpre, h2b, n, D2, st1, st1 + 512, g1, b1);

    // ---- layer 2: 256 -> 128 (project-first, fused [P|R]) ----
    gemm_glds_kernel<false, false, false><<<dim3(2 * D3 / 128, rowBlocks), 256, 0, stream>>>(
        h2b, nullptr, WT2c, nullptr, mb, nullptr, nullptr, n, D2, D2, 2 * D3);
    aggregate_add_kernel<2><<<aggGrid, 256, 0, stream>>>(
        mb, bl2, hpre, rowptr, csr_src, n);                        // pre = mean(P)+R+bl2
    colstats_b_kernel<<<dim3(D3 / 128, 128), 256, 0, stream>>>(hpre, n, D3, st2, st2 + 512);
    bn_relu_b2f_kernel<<<((size_t)n * D3 / 2 + 255) / 256, 256, 0, stream>>>(
        hpre, out, n, D3, st2, st2 + 512, g2, b2);
}

// Round 11
// 592.897 us; speedup vs baseline: 1.1019x; 1.0514x over previous
//
#include <hip/hip_runtime.h>
#include <cstdint>
#include <cstddef>

// ---------------------------------------------------------------------------
// CellGraphSAGE: 3x (SAGE-mean conv -> BN -> ReLU)
// dims: 128 -> 512 -> 256 -> 128, N=50000 nodes, E=800000 edges
// Round 11:
//  - REVERT round-10 fused-colstats GEMM: ~800k contended fp32 atomics ahead
//    of the epilogue __syncthreads (vmcnt drain) stalled the whole block
//    (L0 gemm 58 -> 133 us). L0 colstats is a separate streaming pass again.
//  - keep: merged prep dispatch, bucket CSR, BK=64 glds GEMM + swizzle,
//    wave-per-node gather, bf16 pre-BN pipeline.
// ---------------------------------------------------------------------------

#define EPS_BN 1e-5f

typedef unsigned short ushort_t;
typedef __attribute__((ext_vector_type(8))) short short8;
typedef __attribute__((ext_vector_type(4))) float float4v;

__device__ __forceinline__ float bflo(unsigned int w) {
    union { unsigned int i; float f; } v; v.i = w << 16; return v.f;
}
__device__ __forceinline__ float bfhi(unsigned int w) {
    union { unsigned int i; float f; } v; v.i = w & 0xffff0000u; return v.f;
}
__device__ __forceinline__ ushort_t f2bf(float f) {
    union { float f; unsigned int i; } v; v.f = f;
    unsigned int r = v.i + 0x7fffu + ((v.i >> 16) & 1u);  // RNE
    return (ushort_t)(r >> 16);
}

// async 16B global -> LDS (wave-uniform base + lane*16)
__device__ __forceinline__ void async_copy16(void* lds, const void* g) {
    __builtin_amdgcn_global_load_lds(
        (const __attribute__((address_space(1))) unsigned int*)g,
        (__attribute__((address_space(3))) unsigned int*)lds, 16, 0, 0);
}

// ---------------- edge format hedge (int64 vs int32 storage) ---------------
__global__ void detect_fmt_kernel(const int* __restrict__ edges, int* __restrict__ nz) {
    int t = threadIdx.x;
    int cnt = 0;
    #pragma unroll
    for (int j = 0; j < 4; ++j) {
        int idx = 2 * (t * 4 + j) + 1;
        if (edges[idx] != 0) cnt++;
    }
    if (cnt) atomicAdd(nz, cnt);
}

__device__ __forceinline__ void edge_sd(const int* __restrict__ p, int e, int ne,
                                        bool is64, int& s, int& d) {
    if (is64) { s = p[2 * e];  d = p[2 * ne + 2 * e]; }
    else      { s = p[e];      d = p[ne + e]; }
}
__device__ __forceinline__ int edge_d(const int* __restrict__ p, int e, int ne, bool is64) {
    return is64 ? p[2 * ne + 2 * e] : p[ne + e];
}

// ---------------- bucket-sort CSR build ------------------------------------
#define EPB 2048

__global__ __launch_bounds__(256) void bhist_kernel(
    const int* __restrict__ edges, int ne, const int* __restrict__ nz,
    int* __restrict__ gcnt) {
    __shared__ int h[256];
    int t = threadIdx.x;
    h[t] = 0;
    __syncthreads();
    bool is64 = (*nz == 0);
    int base_e = blockIdx.x * EPB;
    #pragma unroll
    for (int u = 0; u < EPB / 256; ++u) {
        int i = base_e + u * 256 + t;
        if (i < ne) atomicAdd(&h[edge_d(edges, i, ne, is64) >> 8], 1);
    }
    __syncthreads();
    if (h[t]) atomicAdd(&gcnt[t], h[t]);
}

__global__ __launch_bounds__(256) void bscan_kernel(
    const int* __restrict__ gcnt, int nb, int ne,
    int* __restrict__ bbase, int* __restrict__ bcur) {
    __shared__ int sh[256];
    int t = threadIdx.x;
    int v = (t < nb) ? gcnt[t] : 0;
    sh[t] = v;
    __syncthreads();
    for (int o = 1; o < 256; o <<= 1) {
        int x = (t >= o) ? sh[t - o] : 0;
        __syncthreads();
        sh[t] += x;
        __syncthreads();
    }
    int excl = sh[t] - v;
    if (t < nb) { bbase[t] = excl; bcur[t] = excl; }
    if (t == nb) bbase[t] = ne;
    if (t == 0 && nb == 256) bbase[256] = ne;
}

__global__ __launch_bounds__(256) void bscatter_kernel(
    const int* __restrict__ edges, int ne, const int* __restrict__ nz,
    int* __restrict__ bcur, int* __restrict__ packed) {
    __shared__ int h[256];
    __shared__ int chunkb[256];
    __shared__ int lcur[256];
    int t = threadIdx.x;
    h[t] = 0;
    lcur[t] = 0;
    __syncthreads();
    bool is64 = (*nz == 0);
    int base_e = blockIdx.x * EPB;
    int ent[EPB / 256], eb[EPB / 256];
    #pragma unroll
    for (int u = 0; u < EPB / 256; ++u) {
        int i = base_e + u * 256 + t;
        if (i < ne) {
            int s, d;
            edge_sd(edges, i, ne, is64, s, d);
            ent[u] = s | ((d & 255) << 24);
            eb[u] = d >> 8;
            atomicAdd(&h[eb[u]], 1);
        } else eb[u] = -1;
    }
    __syncthreads();
    if (h[t]) chunkb[t] = atomicAdd(&bcur[t], h[t]);
    __syncthreads();
    #pragma unroll
    for (int u = 0; u < EPB / 256; ++u) {
        if (eb[u] >= 0) {
            int lp = atomicAdd(&lcur[eb[u]], 1);
            packed[chunkb[eb[u]] + lp] = ent[u];
        }
    }
}

__global__ __launch_bounds__(256) void bbuild_kernel(
    const int* __restrict__ packed, const int* __restrict__ bbase,
    int* __restrict__ rowptr, int* __restrict__ csr_src, int n) {
    __shared__ int h[256];
    __shared__ int cur[256];
    int t = threadIdx.x;
    int bb = blockIdx.x;
    int base = bbase[bb], cnt = bbase[bb + 1] - base;
    h[t] = 0;
    __syncthreads();
    for (int i = t; i < cnt; i += 256)
        atomicAdd(&h[(unsigned)packed[base + i] >> 24], 1);
    __syncthreads();
    int v = h[t];
    for (int o = 1; o < 256; o <<= 1) {
        int x = (t >= o) ? h[t - o] : 0;
        __syncthreads();
        h[t] += x;
        __syncthreads();
    }
    int excl = h[t] - v;
    int node = bb * 256 + t;
    if (node <= n) rowptr[node] = base + excl;
    cur[t] = excl;
    __syncthreads();
    for (int i = t; i < cnt; i += 256) {
        int e = packed[base + i];
        int lp = atomicAdd(&cur[(unsigned)e >> 24], 1);
        csr_src[base + lp] = e & 0xffffff;
    }
}

// ---------------- merged prep: x->bf16 + 3 transposed weight preps ---------
__global__ void prep_all_kernel(
    const float* __restrict__ x, ushort_t* __restrict__ xb, int nxb,
    const float* __restrict__ Wl0, const float* __restrict__ Wr0,
    ushort_t* __restrict__ WT0, int nb0,   // WT0: D1 x 2*D0 (K-concat)
    const float* __restrict__ Wl1, const float* __restrict__ Wr1,
    ushort_t* __restrict__ WT1c, int nb1,  // WT1c: (2*D2) x D1
    const float* __restrict__ Wl2, const float* __restrict__ Wr2,
    ushort_t* __restrict__ WT2c) {         // WT2c: (2*D3) x D2
    const int D0 = 128, D1 = 512, D2 = 256, D3 = 128;
    int b = blockIdx.x;
    if (b < nxb) {
        int i = b * 256 + threadIdx.x;
        xb[i] = f2bf(x[i]);
        return;
    }
    b -= nxb;
    if (b < nb0) {
        int idx = b * 256 + threadIdx.x;
        int K2 = 2 * D0;
        int nn = idx / K2, k = idx - nn * K2;
        float v = (k < D0) ? Wl0[(size_t)k * D1 + nn] : Wr0[(size_t)(k - D0) * D1 + nn];
        WT0[idx] = f2bf(v);
        return;
    }
    b -= nb0;
    if (b < nb1) {
        int idx = b * 256 + threadIdx.x;
        int nn = idx / D1, k = idx - nn * D1;
        float v = (nn < D2) ? Wl1[(size_t)k * D2 + nn] : Wr1[(size_t)k * D2 + (nn - D2)];
        WT1c[idx] = f2bf(v);
        return;
    }
    b -= nb1;
    {
        int idx = b * 256 + threadIdx.x;
        int nn = idx / D2, k = idx - nn * D2;
        float v = (nn < D3) ? Wl2[(size_t)k * D3 + nn] : Wr2[(size_t)k * D3 + (nn - D3)];
        WT2c[idx] = f2bf(v);
    }
}

// ---------------- aggregation helpers --------------------------------------
template <int VEC> struct VecT;
template <> struct VecT<2> { using T = unsigned int; };
template <> struct VecT<4> { using T = uint2; };
template <> struct VecT<8> { using T = uint4; };

template <int VEC>
__device__ __forceinline__ void vunpack(typename VecT<VEC>::T v, unsigned int* w) {
    if constexpr (VEC == 2) { w[0] = v; }
    else if constexpr (VEC == 4) { w[0] = v.x; w[1] = v.y; }
    else { w[0] = v.x; w[1] = v.y; w[2] = v.z; w[3] = v.w; }
}

template <int VEC>
__device__ __forceinline__ void vaccum(typename VecT<VEC>::T v, float* acc) {
    unsigned int w[VEC / 2];
    vunpack<VEC>(v, w);
    #pragma unroll
    for (int i = 0; i < VEC / 2; ++i) {
        acc[2 * i + 0] += bflo(w[i]);
        acc[2 * i + 1] += bfhi(w[i]);
    }
}

template <int VEC>
__device__ __forceinline__ void gather_sum(
    const ushort_t* __restrict__ base, const int* __restrict__ csr_src,
    int e0, int e1, int rstride, float* acc) {
    using VT = typename VecT<VEC>::T;
    int e = e0;
    for (; e + 8 <= e1; e += 8) {
        VT v[8];
        #pragma unroll
        for (int u = 0; u < 8; ++u)
            v[u] = *(const VT*)(base + (size_t)csr_src[e + u] * rstride);
        #pragma unroll
        for (int u = 0; u < 8; ++u) vaccum<VEC>(v[u], acc);
    }
    if (e + 4 <= e1) {
        VT v[4];
        #pragma unroll
        for (int u = 0; u < 4; ++u)
            v[u] = *(const VT*)(base + (size_t)csr_src[e + u] * rstride);
        #pragma unroll
        for (int u = 0; u < 4; ++u) vaccum<VEC>(v[u], acc);
        e += 4;
    }
    if (e + 2 <= e1) {
        VT v0 = *(const VT*)(base + (size_t)csr_src[e] * rstride);
        VT v1 = *(const VT*)(base + (size_t)csr_src[e + 1] * rstride);
        vaccum<VEC>(v0, acc); vaccum<VEC>(v1, acc);
        e += 2;
    }
    if (e < e1)
        vaccum<VEC>(*(const VT*)(base + (size_t)csr_src[e] * rstride), acc);
}

// ---------------- plain aggregation (layer 0): bf16 mean -------------------
template <int VEC>
__global__ __launch_bounds__(256) void aggregate_wave_kernel(
    const ushort_t* __restrict__ h, ushort_t* __restrict__ mean,
    const int* __restrict__ rowptr, const int* __restrict__ csr_src, int nnodes) {
    const int din = VEC * 64;
    int wid = blockIdx.x * 4 + (threadIdx.x >> 6);
    if (wid >= nnodes) return;
    int lane = threadIdx.x & 63;
    int e0 = rowptr[wid], e1 = rowptr[wid + 1];

    float acc[VEC];
    #pragma unroll
    for (int i = 0; i < VEC; ++i) acc[i] = 0.f;
    gather_sum<VEC>(h + (size_t)lane * VEC, csr_src, e0, e1, din, acc);

    int deg = e1 - e0;
    float scale = 1.0f / (float)(deg > 1 ? deg : 1);
    unsigned int o[VEC / 2];
    #pragma unroll
    for (int i = 0; i < VEC / 2; ++i)
        o[i] = (unsigned int)f2bf(acc[2 * i] * scale) |
               ((unsigned int)f2bf(acc[2 * i + 1] * scale) << 16);
    using VT = typename VecT<VEC>::T;
    VT ov;
    if constexpr (VEC == 2) { ov = o[0]; }
    else if constexpr (VEC == 4) { ov.x = o[0]; ov.y = o[1]; }
    else { ov.x = o[0]; ov.y = o[1]; ov.z = o[2]; ov.w = o[3]; }
    *(VT*)(mean + (size_t)wid * din + (size_t)lane * VEC) = ov;
}

// ---------------- fused aggregate + add, bf16 out (layers 1/2) -------------
template <int VEC>  // VEC = D/64
__global__ __launch_bounds__(256) void aggregate_add_kernel(
    const ushort_t* __restrict__ PR, const float* __restrict__ bias,
    ushort_t* __restrict__ pre,
    const int* __restrict__ rowptr, const int* __restrict__ csr_src, int nnodes) {
    const int D = VEC * 64;
    const int stride = 2 * D;
    int wid = blockIdx.x * 4 + (threadIdx.x >> 6);
    if (wid >= nnodes) return;
    int lane = threadIdx.x & 63;
    int e0 = rowptr[wid], e1 = rowptr[wid + 1];

    float acc[VEC];
    #pragma unroll
    for (int i = 0; i < VEC; ++i) acc[i] = 0.f;
    gather_sum<VEC>(PR + (size_t)lane * VEC, csr_src, e0, e1, stride, acc);

    int deg = e1 - e0;
    float scale = 1.0f / (float)(deg > 1 ? deg : 1);

    using VT = typename VecT<VEC>::T;
    VT rv = *(const VT*)(PR + (size_t)wid * stride + D + (size_t)lane * VEC);
    unsigned int rw[VEC / 2];
    vunpack<VEC>(rv, rw);
    float o[VEC];
    #pragma unroll
    for (int i = 0; i < VEC / 2; ++i) {
        o[2 * i + 0] = bflo(rw[i]);
        o[2 * i + 1] = bfhi(rw[i]);
    }
    #pragma unroll
    for (int i = 0; i < VEC; ++i)
        o[i] += acc[i] * scale + bias[lane * VEC + i];

    unsigned int ow[VEC / 2];
    #pragma unroll
    for (int i = 0; i < VEC / 2; ++i)
        ow[i] = (unsigned int)f2bf(o[2 * i]) | ((unsigned int)f2bf(o[2 * i + 1]) << 16);
    VT ov;
    if constexpr (VEC == 2) { ov = ow[0]; }
    else if constexpr (VEC == 4) { ov.x = ow[0]; ov.y = ow[1]; }
    else { ov.x = ow[0]; ov.y = ow[1]; ov.z = ow[2]; ov.w = ow[3]; }
    *(VT*)(pre + (size_t)wid * D + (size_t)lane * VEC) = ov;
}

// ---------------- MFMA GEMM, BK=64, global_load_lds + 3-bit swizzle --------
// DUAL: C = [A1|A2] @ BT^T ; BIAS adds bias[col]; bf16 out via LDS restage.
// NOTE: no global atomics in this kernel — contended atomics before the
// epilogue barriers serialize the block on vmcnt drain (round-10 lesson).
template <bool DUAL, bool BIAS>
__global__ __launch_bounds__(256) void gemm_glds_kernel(
    const ushort_t* __restrict__ A1, const ushort_t* __restrict__ A2,
    const ushort_t* __restrict__ BT, const float* __restrict__ bias,
    ushort_t* __restrict__ Cb, int N, int K1, int Ktot, int Wtot) {
    __shared__ ushort_t As[128 * 64];  // 16 KB
    __shared__ ushort_t Bs[128 * 64];  // 16 KB

    const int tid = threadIdx.x;
    const int wave = tid >> 6;
    const int lane = tid & 63;
    const int quad = lane >> 4;
    const int l15 = lane & 15;
    const int sw7 = l15 & 7;
    const int rowBase = blockIdx.y * 128;
    const int colBase = blockIdx.x * 128;
    const int wm = (wave >> 1) * 64;
    const int wn = (wave & 1) * 64;

    float4v acc[4][4];
    #pragma unroll
    for (int i = 0; i < 4; ++i)
        #pragma unroll
        for (int j = 0; j < 4; ++j)
            acc[i][j] = (float4v){0.f, 0.f, 0.f, 0.f};

    const int nkt = Ktot / 64;
    const int khalf = K1 / 64;

    for (int kt = 0; kt < nkt; ++kt) {
        const ushort_t* Asrc = A1;
        int kg = kt * 64;
        if (DUAL && kt >= khalf) { Asrc = A2; kg = (kt - khalf) * 64; }
        const int kb = kt * 64;

        #pragma unroll
        for (int u = 0; u < 4; ++u) {
            int c = u * 256 + tid;
            int r = c >> 3, cc = c & 7;
            int off = (cc ^ (r & 7)) * 8;
            int grow = rowBase + r;
            if (grow >= N) grow = N - 1;
            async_copy16(&As[c * 8], Asrc + (size_t)grow * K1 + kg + off);
            async_copy16(&Bs[c * 8], BT + (size_t)(colBase + r) * Ktot + kb + off);
        }
        __syncthreads();

        #pragma unroll
        for (int kh = 0; kh < 2; ++kh) {
            int cidx = kh * 4 + quad;
            short8 af[4], bf4[4];
            #pragma unroll
            for (int i = 0; i < 4; ++i)
                af[i] = *(const short8*)&As[(wm + i * 16 + l15) * 64 + (cidx ^ sw7) * 8];
            #pragma unroll
            for (int j = 0; j < 4; ++j)
                bf4[j] = *(const short8*)&Bs[(wn + j * 16 + l15) * 64 + (cidx ^ sw7) * 8];
            // operand swap: acc[i][j][r] = C[wm+i*16+l15][wn+j*16+quad*4+r]
            #pragma unroll
            for (int i = 0; i < 4; ++i)
                #pragma unroll
                for (int j = 0; j < 4; ++j)
                    acc[i][j] = __builtin_amdgcn_mfma_f32_16x16x32_bf16(bf4[j], af[i], acc[i][j], 0, 0, 0);
        }
        __syncthreads();
    }

    // epilogue: per-wave 4KB LDS restage -> full-line bf16 stores
    ushort_t* lws = &As[wave * 2048];
    #pragma unroll
    for (int p = 0; p < 2; ++p) {
        #pragma unroll
        for (int jj = 0; jj < 2; ++jj) {
            int j = 2 * p + jj;
            float4 bv = make_float4(0.f, 0.f, 0.f, 0.f);
            if (BIAS) bv = *(const float4*)(bias + colBase + wn + j * 16 + quad * 4);
            #pragma unroll
            for (int i = 0; i < 4; ++i) {
                uint2 pk;
                pk.x = (unsigned int)f2bf(acc[i][j][0] + bv.x) |
                       ((unsigned int)f2bf(acc[i][j][1] + bv.y) << 16);
                pk.y = (unsigned int)f2bf(acc[i][j][2] + bv.z) |
                       ((unsigned int)f2bf(acc[i][j][3] + bv.w) << 16);
                *(uint2*)&lws[(i * 16 + l15) * 32 + jj * 16 + quad * 4] = pk;
            }
        }
        __syncthreads();
        #pragma unroll
        for (int it = 0; it < 4; ++it) {
            int c = it * 64 + lane;
            int row = c >> 2, coff = (c & 3) * 8;
            int grow = rowBase + wm + row;
            if (grow < N) {
                uint4 v = *(const uint4*)&lws[row * 32 + coff];
                *(uint4*)(Cb + (size_t)grow * Wtot + colBase + wn + p * 32 + coff) = v;
            }
        }
        __syncthreads();
    }
}

// ---------------- BN stats (bf16 input) ------------------------------------
__global__ void colstats_b_kernel(const ushort_t* __restrict__ h, int N, int D,
                                  float* __restrict__ sum, float* __restrict__ sumsq) {
    int c2 = blockIdx.x * 128 + (threadIdx.x & 63) * 2;
    int rl = threadIdx.x >> 6;
    float s0 = 0.f, s20 = 0.f, s1 = 0.f, s21 = 0.f;
    int stride = gridDim.y * 4;
    for (int r = blockIdx.y * 4 + rl; r < N; r += stride) {
        unsigned int w = *(const unsigned int*)(h + (size_t)r * D + c2);
        float v0 = bflo(w), v1 = bfhi(w);
        s0 += v0; s20 += v0 * v0;
        s1 += v1; s21 += v1 * v1;
    }
    atomicAdd(&sum[c2 + 0], s0);
    atomicAdd(&sumsq[c2 + 0], s20);
    atomicAdd(&sum[c2 + 1], s1);
    atomicAdd(&sumsq[c2 + 1], s21);
}

// ---------------- BN apply (bf16 in) ---------------------------------------
__global__ void bn_relu_b2b_kernel(const ushort_t* __restrict__ h, ushort_t* __restrict__ hb,
                                   int N, int D,
                                   const float* __restrict__ sum, const float* __restrict__ sumsq,
                                   const float* __restrict__ g, const float* __restrict__ b) {
    size_t idx = (size_t)blockIdx.x * blockDim.x + threadIdx.x;
    size_t tot = (size_t)N * D / 2;
    if (idx >= tot) return;
    int cp = (int)(idx & (size_t)(D / 2 - 1));
    int c0 = cp * 2, c1 = c0 + 1;
    float m0 = sum[c0] / (float)N, m1 = sum[c1] / (float)N;
    float i0 = rsqrtf(sumsq[c0] / (float)N - m0 * m0 + EPS_BN);
    float i1 = rsqrtf(sumsq[c1] / (float)N - m1 * m1 + EPS_BN);
    unsigned int w = ((const unsigned int*)h)[idx];
    float v0 = g[c0] * (bflo(w) - m0) * i0 + b[c0];
    float v1 = g[c1] * (bfhi(w) - m1) * i1 + b[c1];
    v0 = v0 > 0.f ? v0 : 0.f;
    v1 = v1 > 0.f ? v1 : 0.f;
    ((unsigned int*)hb)[idx] = (unsigned int)f2bf(v0) | ((unsigned int)f2bf(v1) << 16);
}

__global__ void bn_relu_b2f_kernel(const ushort_t* __restrict__ h, float* __restrict__ hf,
                                   int N, int D,
                                   const float* __restrict__ sum, const float* __restrict__ sumsq,
                                   const float* __restrict__ g, const float* __restrict__ b) {
    size_t idx = (size_t)blockIdx.x * blockDim.x + threadIdx.x;
    size_t tot = (size_t)N * D / 2;
    if (idx >= tot) return;
    int cp = (int)(idx & (size_t)(D / 2 - 1));
    int c0 = cp * 2, c1 = c0 + 1;
    float m0 = sum[c0] / (float)N, m1 = sum[c1] / (float)N;
    float i0 = rsqrtf(sumsq[c0] / (float)N - m0 * m0 + EPS_BN);
    float i1 = rsqrtf(sumsq[c1] / (float)N - m1 * m1 + EPS_BN);
    unsigned int w = ((const unsigned int*)h)[idx];
    float v0 = g[c0] * (bflo(w) - m0) * i0 + b[c0];
    float v1 = g[c1] * (bfhi(w) - m1) * i1 + b[c1];
    float2 o;
    o.x = v0 > 0.f ? v0 : 0.f;
    o.y = v1 > 0.f ? v1 : 0.f;
    *(float2*)(hf + idx * 2) = o;
}

// ---------------------------------------------------------------------------
extern "C" void kernel_launch(void* const* d_in, const int* in_sizes, int n_in,
                              void* d_out, int out_size, void* d_ws, size_t ws_size,
                              hipStream_t stream) {
    const float* x     = (const float*)d_in[0];
    const int*   edges = (const int*)d_in[1];
    const float* Wl0 = (const float*)d_in[2];
    const float* bl0 = (const float*)d_in[3];
    const float* Wr0 = (const float*)d_in[4];
    const float* g0  = (const float*)d_in[5];
    const float* b0  = (const float*)d_in[6];
    const float* Wl1 = (const float*)d_in[7];
    const float* bl1 = (const float*)d_in[8];
    const float* Wr1 = (const float*)d_in[9];
    const float* g1  = (const float*)d_in[10];
    const float* b1  = (const float*)d_in[11];
    const float* Wl2 = (const float*)d_in[12];
    const float* bl2 = (const float*)d_in[13];
    const float* Wr2 = (const float*)d_in[14];
    const float* g2  = (const float*)d_in[15];
    const float* b2  = (const float*)d_in[16];

    const int D0 = 128, D1 = 512, D2 = 256, D3 = 128;
    const int n  = in_sizes[0] / D0;   // 50000
    const int ne = in_sizes[1] / 2;    // 800000
    const int NB = (n + 255) >> 8;     // 196 buckets

    // ---- workspace layout (zeroed block first -> one memset) ----
    char* base = (char*)d_ws;
    size_t off = 0;
    auto alloc = [&](size_t bytes) -> char* {
        char* p = base + off;
        off = (off + bytes + 255) & ~(size_t)255;
        return p;
    };
    int*      nzflag  = (int*)alloc(4);
    int*      gcnt    = (int*)alloc(256 * 4);
    float*    stats   = (float*)alloc(6 * 512 * 4);
    size_t    zero_span = off;
    int*      bbase   = (int*)alloc(257 * 4);
    int*      bcur    = (int*)alloc(256 * 4);
    int*      packed  = (int*)alloc((size_t)ne * 4);
    int*      rowptr  = (int*)alloc((size_t)(n + 1) * 4);
    int*      csr_src = (int*)alloc((size_t)ne * 4);
    ushort_t* xb      = (ushort_t*)alloc((size_t)n * D0 * 2);
    ushort_t* mb      = (ushort_t*)alloc((size_t)n * 512 * 2);   // mean(L0) / PR(L1,L2)
    ushort_t* h1b     = (ushort_t*)alloc((size_t)n * D1 * 2);
    ushort_t* h2b     = (ushort_t*)alloc((size_t)n * D2 * 2);
    ushort_t* hpre    = (ushort_t*)alloc((size_t)n * 512 * 2);   // bf16 pre-BN
    ushort_t* WT0     = (ushort_t*)alloc((size_t)D1 * 2 * D0 * 2);
    ushort_t* WT1c    = (ushort_t*)alloc((size_t)(2 * D2) * D1 * 2);
    ushort_t* WT2c    = (ushort_t*)alloc((size_t)(2 * D3) * D2 * 2);
    float*    out     = (float*)d_out;
    (void)ws_size; (void)n_in; (void)out_size;

    hipMemsetAsync(base, 0, zero_span, stream);

    // ---- edge format detection + bucket-sort CSR build ----
    detect_fmt_kernel<<<1, 256, 0, stream>>>(edges, nzflag);
    int ablk = (ne + EPB - 1) / EPB;
    bhist_kernel<<<ablk, 256, 0, stream>>>(edges, ne, nzflag, gcnt);
    bscan_kernel<<<1, 256, 0, stream>>>(gcnt, NB, ne, bbase, bcur);
    bscatter_kernel<<<ablk, 256, 0, stream>>>(edges, ne, nzflag, bcur, packed);
    bbuild_kernel<<<NB, 256, 0, stream>>>(packed, bbase, rowptr, csr_src, n);

    // ---- merged prep (x->bf16 + all weight transposes) ----
    const int nxb = (n * D0) / 256;               // 25000
    const int nb0 = (D1 * 2 * D0) / 256;          // 512
    const int nb1 = (2 * D2 * D1) / 256;          // 1024
    const int nb2 = (2 * D3 * D2) / 256;          // 256
    prep_all_kernel<<<nxb + nb0 + nb1 + nb2, 256, 0, stream>>>(
        x, xb, nxb, Wl0, Wr0, WT0, nb0, Wl1, Wr1, WT1c, nb1, Wl2, Wr2, WT2c);

    const int aggGrid = (n + 3) / 4;
    const int rowBlocks = (n + 127) / 128;
    float* st0 = stats + 0 * 1024;
    float* st1 = stats + 1 * 1024;
    float* st2 = stats + 2 * 1024;

    // ---- layer 0: 128 -> 512 (aggregate-first: din < dout) ----
    aggregate_wave_kernel<2><<<aggGrid, 256, 0, stream>>>(xb, mb, rowptr, csr_src, n);
    gemm_glds_kernel<true, true><<<dim3(D1 / 128, rowBlocks), 256, 0, stream>>>(
        mb, xb, WT0, bl0, hpre, n, D0, 2 * D0, D1);
    colstats_b_kernel<<<dim3(D1 / 128, 128), 256, 0, stream>>>(hpre, n, D1, st0, st0 + 512);
    bn_relu_b2b_kernel<<<((size_t)n * D1 / 2 + 255) / 256, 256, 0, stream>>>(
        hpre, h1b, n, D1, st0, st0 + 512, g0, b0);

    // ---- layer 1: 512 -> 256 (project-first, fused [P|R]) ----
    gemm_glds_kernel<false, false><<<dim3(2 * D2 / 128, rowBlocks), 256, 0, stream>>>(
        h1b, nullptr, WT1c, nullptr, mb, n, D1, D1, 2 * D2);      // PR1 = h1 @ [Wl1|Wr1]
    aggregate_add_kernel<4><<<aggGrid, 256, 0, stream>>>(
        mb, bl1, hpre, rowptr, csr_src, n);                        // pre = mean(P)+R+bl1
    colstats_b_kernel<<<dim3(D2 / 128, 128), 256, 0, stream>>>(hpre, n, D2, st1, st1 + 512);
    bn_relu_b2b_kernel<<<((size_t)n * D2 / 2 + 255) / 256, 256, 0, stream>>>(
        hpre, h2b, n, D2, st1, st1 + 512, g1, b1);

    // ---- layer 2: 256 -> 128 (project-first, fused [P|R]) ----
    gemm_glds_kernel<false, false><<<dim3(2 * D3 / 128, rowBlocks), 256, 0, stream>>>(
        h2b, nullptr, WT2c, nullptr, mb, n, D2, D2, 2 * D3);      // PR2 = h2 @ [Wl2|Wr2]
    aggregate_add_kernel<2><<<aggGrid, 256, 0, stream>>>(
        mb, bl2, hpre, rowptr, csr_src, n);                        // pre = mean(P)+R+bl2
    colstats_b_kernel<<<dim3(D3 / 128, 128), 256, 0, stream>>>(hpre, n, D3, st2, st2 + 512);
    bn_relu_b2f_kernel<<<((size_t)n * D3 / 2 + 255) / 256, 256, 0, stream>>>(
        hpre, out, n, D3, st2, st2 + 512, g2, b2);
}

// Round 12
// 584.488 us; speedup vs baseline: 1.1178x; 1.0144x over previous
//
#include <hip/hip_runtime.h>
#include <cstdint>
#include <cstddef>

// ---------------------------------------------------------------------------
// CellGraphSAGE: 3x (SAGE-mean conv -> BN -> ReLU)
// dims: 128 -> 512 -> 256 -> 128, N=50000 nodes, E=800000 edges
// Round 12:
//  - GEMM tile 256x128 (512 threads, 8 waves): 2x MFMA per barrier, half the
//    B-staging per FLOP. 48 KB LDS -> 3 blocks/CU.
//  - gather main loop unrolled x16 (more MLP for the latency-bound gather)
//  - int64/int32 edge detection inlined into bhist/bscatter (one fewer
//    dispatch; LDS-flag probe of 64 odd words per block)
// ---------------------------------------------------------------------------

#define EPS_BN 1e-5f

typedef unsigned short ushort_t;
typedef __attribute__((ext_vector_type(8))) short short8;
typedef __attribute__((ext_vector_type(4))) float float4v;

__device__ __forceinline__ float bflo(unsigned int w) {
    union { unsigned int i; float f; } v; v.i = w << 16; return v.f;
}
__device__ __forceinline__ float bfhi(unsigned int w) {
    union { unsigned int i; float f; } v; v.i = w & 0xffff0000u; return v.f;
}
__device__ __forceinline__ ushort_t f2bf(float f) {
    union { float f; unsigned int i; } v; v.f = f;
    unsigned int r = v.i + 0x7fffu + ((v.i >> 16) & 1u);  // RNE
    return (ushort_t)(r >> 16);
}

// async 16B global -> LDS (wave-uniform base + lane*16)
__device__ __forceinline__ void async_copy16(void* lds, const void* g) {
    __builtin_amdgcn_global_load_lds(
        (const __attribute__((address_space(1))) unsigned int*)g,
        (__attribute__((address_space(3))) unsigned int*)lds, 16, 0, 0);
}

__device__ __forceinline__ void edge_sd(const int* __restrict__ p, int e, int ne,
                                        bool is64, int& s, int& d) {
    if (is64) { s = p[2 * e];  d = p[2 * ne + 2 * e]; }
    else      { s = p[e];      d = p[ne + e]; }
}
__device__ __forceinline__ int edge_d(const int* __restrict__ p, int e, int ne, bool is64) {
    return is64 ? p[2 * ne + 2 * e] : p[ne + e];
}

// in-block edge-format probe: int64 storage (values < 2^31) => odd int32
// words are all 0; random int32 ids make 64 consecutive zeros impossible.
__device__ __forceinline__ bool detect_is64(const int* __restrict__ edges,
                                            int* sh_flag, int t) {
    if (t == 0) *sh_flag = 1;
    __syncthreads();
    if (t < 64 && edges[2 * t + 1] != 0) *sh_flag = 0;  // same-value race ok
    __syncthreads();
    return *sh_flag != 0;
}

// ---------------- bucket-sort CSR build ------------------------------------
#define EPB 2048

__global__ __launch_bounds__(256) void bhist_kernel(
    const int* __restrict__ edges, int ne, int* __restrict__ gcnt) {
    __shared__ int h[256];
    __shared__ int f64;
    int t = threadIdx.x;
    bool is64 = detect_is64(edges, &f64, t);
    h[t] = 0;
    __syncthreads();
    int base_e = blockIdx.x * EPB;
    #pragma unroll
    for (int u = 0; u < EPB / 256; ++u) {
        int i = base_e + u * 256 + t;
        if (i < ne) atomicAdd(&h[edge_d(edges, i, ne, is64) >> 8], 1);
    }
    __syncthreads();
    if (h[t]) atomicAdd(&gcnt[t], h[t]);
}

__global__ __launch_bounds__(256) void bscan_kernel(
    const int* __restrict__ gcnt, int nb, int ne,
    int* __restrict__ bbase, int* __restrict__ bcur) {
    __shared__ int sh[256];
    int t = threadIdx.x;
    int v = (t < nb) ? gcnt[t] : 0;
    sh[t] = v;
    __syncthreads();
    for (int o = 1; o < 256; o <<= 1) {
        int x = (t >= o) ? sh[t - o] : 0;
        __syncthreads();
        sh[t] += x;
        __syncthreads();
    }
    int excl = sh[t] - v;
    if (t < nb) { bbase[t] = excl; bcur[t] = excl; }
    if (t == nb) bbase[t] = ne;
    if (t == 0 && nb == 256) bbase[256] = ne;
}

__global__ __launch_bounds__(256) void bscatter_kernel(
    const int* __restrict__ edges, int ne,
    int* __restrict__ bcur, int* __restrict__ packed) {
    __shared__ int h[256];
    __shared__ int chunkb[256];
    __shared__ int lcur[256];
    __shared__ int f64;
    int t = threadIdx.x;
    bool is64 = detect_is64(edges, &f64, t);
    h[t] = 0;
    lcur[t] = 0;
    __syncthreads();
    int base_e = blockIdx.x * EPB;
    int ent[EPB / 256], eb[EPB / 256];
    #pragma unroll
    for (int u = 0; u < EPB / 256; ++u) {
        int i = base_e + u * 256 + t;
        if (i < ne) {
            int s, d;
            edge_sd(edges, i, ne, is64, s, d);
            ent[u] = s | ((d & 255) << 24);
            eb[u] = d >> 8;
            atomicAdd(&h[eb[u]], 1);
        } else eb[u] = -1;
    }
    __syncthreads();
    if (h[t]) chunkb[t] = atomicAdd(&bcur[t], h[t]);
    __syncthreads();
    #pragma unroll
    for (int u = 0; u < EPB / 256; ++u) {
        if (eb[u] >= 0) {
            int lp = atomicAdd(&lcur[eb[u]], 1);
            packed[chunkb[eb[u]] + lp] = ent[u];
        }
    }
}

__global__ __launch_bounds__(256) void bbuild_kernel(
    const int* __restrict__ packed, const int* __restrict__ bbase,
    int* __restrict__ rowptr, int* __restrict__ csr_src, int n) {
    __shared__ int h[256];
    __shared__ int cur[256];
    int t = threadIdx.x;
    int bb = blockIdx.x;
    int base = bbase[bb], cnt = bbase[bb + 1] - base;
    h[t] = 0;
    __syncthreads();
    for (int i = t; i < cnt; i += 256)
        atomicAdd(&h[(unsigned)packed[base + i] >> 24], 1);
    __syncthreads();
    int v = h[t];
    for (int o = 1; o < 256; o <<= 1) {
        int x = (t >= o) ? h[t - o] : 0;
        __syncthreads();
        h[t] += x;
        __syncthreads();
    }
    int excl = h[t] - v;
    int node = bb * 256 + t;
    if (node <= n) rowptr[node] = base + excl;
    cur[t] = excl;
    __syncthreads();
    for (int i = t; i < cnt; i += 256) {
        int e = packed[base + i];
        int lp = atomicAdd(&cur[(unsigned)e >> 24], 1);
        csr_src[base + lp] = e & 0xffffff;
    }
}

// ---------------- merged prep: x->bf16 + 3 transposed weight preps ---------
__global__ void prep_all_kernel(
    const float* __restrict__ x, ushort_t* __restrict__ xb, int nxb,
    const float* __restrict__ Wl0, const float* __restrict__ Wr0,
    ushort_t* __restrict__ WT0, int nb0,
    const float* __restrict__ Wl1, const float* __restrict__ Wr1,
    ushort_t* __restrict__ WT1c, int nb1,
    const float* __restrict__ Wl2, const float* __restrict__ Wr2,
    ushort_t* __restrict__ WT2c) {
    const int D0 = 128, D1 = 512, D2 = 256, D3 = 128;
    int b = blockIdx.x;
    if (b < nxb) {
        int i = b * 256 + threadIdx.x;
        xb[i] = f2bf(x[i]);
        return;
    }
    b -= nxb;
    if (b < nb0) {
        int idx = b * 256 + threadIdx.x;
        int K2 = 2 * D0;
        int nn = idx / K2, k = idx - nn * K2;
        float v = (k < D0) ? Wl0[(size_t)k * D1 + nn] : Wr0[(size_t)(k - D0) * D1 + nn];
        WT0[idx] = f2bf(v);
        return;
    }
    b -= nb0;
    if (b < nb1) {
        int idx = b * 256 + threadIdx.x;
        int nn = idx / D1, k = idx - nn * D1;
        float v = (nn < D2) ? Wl1[(size_t)k * D2 + nn] : Wr1[(size_t)k * D2 + (nn - D2)];
        WT1c[idx] = f2bf(v);
        return;
    }
    b -= nb1;
    {
        int idx = b * 256 + threadIdx.x;
        int nn = idx / D2, k = idx - nn * D2;
        float v = (nn < D3) ? Wl2[(size_t)k * D3 + nn] : Wr2[(size_t)k * D3 + (nn - D3)];
        WT2c[idx] = f2bf(v);
    }
}

// ---------------- aggregation helpers --------------------------------------
template <int VEC> struct VecT;
template <> struct VecT<2> { using T = unsigned int; };
template <> struct VecT<4> { using T = uint2; };
template <> struct VecT<8> { using T = uint4; };

template <int VEC>
__device__ __forceinline__ void vunpack(typename VecT<VEC>::T v, unsigned int* w) {
    if constexpr (VEC == 2) { w[0] = v; }
    else if constexpr (VEC == 4) { w[0] = v.x; w[1] = v.y; }
    else { w[0] = v.x; w[1] = v.y; w[2] = v.z; w[3] = v.w; }
}

template <int VEC>
__device__ __forceinline__ void vaccum(typename VecT<VEC>::T v, float* acc) {
    unsigned int w[VEC / 2];
    vunpack<VEC>(v, w);
    #pragma unroll
    for (int i = 0; i < VEC / 2; ++i) {
        acc[2 * i + 0] += bflo(w[i]);
        acc[2 * i + 1] += bfhi(w[i]);
    }
}

// gather loop, x16 main unroll with cascade tail (order-preserving)
template <int VEC>
__device__ __forceinline__ void gather_sum(
    const ushort_t* __restrict__ base, const int* __restrict__ csr_src,
    int e0, int e1, int rstride, float* acc) {
    using VT = typename VecT<VEC>::T;
    int e = e0;
    for (; e + 16 <= e1; e += 16) {
        VT v[16];
        #pragma unroll
        for (int u = 0; u < 16; ++u)
            v[u] = *(const VT*)(base + (size_t)csr_src[e + u] * rstride);
        #pragma unroll
        for (int u = 0; u < 16; ++u) vaccum<VEC>(v[u], acc);
    }
    if (e + 8 <= e1) {
        VT v[8];
        #pragma unroll
        for (int u = 0; u < 8; ++u)
            v[u] = *(const VT*)(base + (size_t)csr_src[e + u] * rstride);
        #pragma unroll
        for (int u = 0; u < 8; ++u) vaccum<VEC>(v[u], acc);
        e += 8;
    }
    if (e + 4 <= e1) {
        VT v[4];
        #pragma unroll
        for (int u = 0; u < 4; ++u)
            v[u] = *(const VT*)(base + (size_t)csr_src[e + u] * rstride);
        #pragma unroll
        for (int u = 0; u < 4; ++u) vaccum<VEC>(v[u], acc);
        e += 4;
    }
    if (e + 2 <= e1) {
        VT v0 = *(const VT*)(base + (size_t)csr_src[e] * rstride);
        VT v1 = *(const VT*)(base + (size_t)csr_src[e + 1] * rstride);
        vaccum<VEC>(v0, acc); vaccum<VEC>(v1, acc);
        e += 2;
    }
    if (e < e1)
        vaccum<VEC>(*(const VT*)(base + (size_t)csr_src[e] * rstride), acc);
}

// ---------------- plain aggregation (layer 0): bf16 mean -------------------
template <int VEC>
__global__ __launch_bounds__(256) void aggregate_wave_kernel(
    const ushort_t* __restrict__ h, ushort_t* __restrict__ mean,
    const int* __restrict__ rowptr, const int* __restrict__ csr_src, int nnodes) {
    const int din = VEC * 64;
    int wid = blockIdx.x * 4 + (threadIdx.x >> 6);
    if (wid >= nnodes) return;
    int lane = threadIdx.x & 63;
    int e0 = rowptr[wid], e1 = rowptr[wid + 1];

    float acc[VEC];
    #pragma unroll
    for (int i = 0; i < VEC; ++i) acc[i] = 0.f;
    gather_sum<VEC>(h + (size_t)lane * VEC, csr_src, e0, e1, din, acc);

    int deg = e1 - e0;
    float scale = 1.0f / (float)(deg > 1 ? deg : 1);
    unsigned int o[VEC / 2];
    #pragma unroll
    for (int i = 0; i < VEC / 2; ++i)
        o[i] = (unsigned int)f2bf(acc[2 * i] * scale) |
               ((unsigned int)f2bf(acc[2 * i + 1] * scale) << 16);
    using VT = typename VecT<VEC>::T;
    VT ov;
    if constexpr (VEC == 2) { ov = o[0]; }
    else if constexpr (VEC == 4) { ov.x = o[0]; ov.y = o[1]; }
    else { ov.x = o[0]; ov.y = o[1]; ov.z = o[2]; ov.w = o[3]; }
    *(VT*)(mean + (size_t)wid * din + (size_t)lane * VEC) = ov;
}

// ---------------- fused aggregate + add, bf16 out (layers 1/2) -------------
template <int VEC>  // VEC = D/64
__global__ __launch_bounds__(256) void aggregate_add_kernel(
    const ushort_t* __restrict__ PR, const float* __restrict__ bias,
    ushort_t* __restrict__ pre,
    const int* __restrict__ rowptr, const int* __restrict__ csr_src, int nnodes) {
    const int D = VEC * 64;
    const int stride = 2 * D;
    int wid = blockIdx.x * 4 + (threadIdx.x >> 6);
    if (wid >= nnodes) return;
    int lane = threadIdx.x & 63;
    int e0 = rowptr[wid], e1 = rowptr[wid + 1];

    float acc[VEC];
    #pragma unroll
    for (int i = 0; i < VEC; ++i) acc[i] = 0.f;
    gather_sum<VEC>(PR + (size_t)lane * VEC, csr_src, e0, e1, stride, acc);

    int deg = e1 - e0;
    float scale = 1.0f / (float)(deg > 1 ? deg : 1);

    using VT = typename VecT<VEC>::T;
    VT rv = *(const VT*)(PR + (size_t)wid * stride + D + (size_t)lane * VEC);
    unsigned int rw[VEC / 2];
    vunpack<VEC>(rv, rw);
    float o[VEC];
    #pragma unroll
    for (int i = 0; i < VEC / 2; ++i) {
        o[2 * i + 0] = bflo(rw[i]);
        o[2 * i + 1] = bfhi(rw[i]);
    }
    #pragma unroll
    for (int i = 0; i < VEC; ++i)
        o[i] += acc[i] * scale + bias[lane * VEC + i];

    unsigned int ow[VEC / 2];
    #pragma unroll
    for (int i = 0; i < VEC / 2; ++i)
        ow[i] = (unsigned int)f2bf(o[2 * i]) | ((unsigned int)f2bf(o[2 * i + 1]) << 16);
    VT ov;
    if constexpr (VEC == 2) { ov = ow[0]; }
    else if constexpr (VEC == 4) { ov.x = ow[0]; ov.y = ow[1]; }
    else { ov.x = ow[0]; ov.y = ow[1]; ov.z = ow[2]; ov.w = ow[3]; }
    *(VT*)(pre + (size_t)wid * D + (size_t)lane * VEC) = ov;
}

// ---------------- MFMA GEMM, 256x128 tile, 512 threads, BK=64 --------------
// DUAL: C = [A1|A2] @ BT^T ; BIAS adds bias[col]; bf16 out via LDS restage.
// 8 waves: wave -> (wm = (wave>>1)*64, wn = (wave&1)*64). LDS 48 KB.
// No global atomics here (round-10 lesson: atomics before barriers stall).
template <bool DUAL, bool BIAS>
__global__ __launch_bounds__(512) void gemm_glds_kernel(
    const ushort_t* __restrict__ A1, const ushort_t* __restrict__ A2,
    const ushort_t* __restrict__ BT, const float* __restrict__ bias,
    ushort_t* __restrict__ Cb, int N, int K1, int Ktot, int Wtot) {
    __shared__ ushort_t As[256 * 64];  // 32 KB
    __shared__ ushort_t Bs[128 * 64];  // 16 KB

    const int tid = threadIdx.x;
    const int wave = tid >> 6;
    const int lane = tid & 63;
    const int quad = lane >> 4;
    const int l15 = lane & 15;
    const int sw7 = l15 & 7;
    const int rowBase = blockIdx.y * 256;
    const int colBase = blockIdx.x * 128;
    const int wm = (wave >> 1) * 64;   // 0..192
    const int wn = (wave & 1) * 64;    // 0/64

    float4v acc[4][4];
    #pragma unroll
    for (int i = 0; i < 4; ++i)
        #pragma unroll
        for (int j = 0; j < 4; ++j)
            acc[i][j] = (float4v){0.f, 0.f, 0.f, 0.f};

    const int nkt = Ktot / 64;
    const int khalf = K1 / 64;

    for (int kt = 0; kt < nkt; ++kt) {
        const ushort_t* Asrc = A1;
        int kg = kt * 64;
        if (DUAL && kt >= khalf) { Asrc = A2; kg = (kt - khalf) * 64; }
        const int kb = kt * 64;

        // A: 2048 chunks of 16B (256 rows x 8); B: 1024 chunks (128 rows x 8)
        #pragma unroll
        for (int u = 0; u < 4; ++u) {
            int c = u * 512 + tid;
            int r = c >> 3, cc = c & 7;
            int off = (cc ^ (r & 7)) * 8;
            int grow = rowBase + r;
            if (grow >= N) grow = N - 1;
            async_copy16(&As[c * 8], Asrc + (size_t)grow * K1 + kg + off);
        }
        #pragma unroll
        for (int u = 0; u < 2; ++u) {
            int c = u * 512 + tid;
            int r = c >> 3, cc = c & 7;
            int off = (cc ^ (r & 7)) * 8;
            async_copy16(&Bs[c * 8], BT + (size_t)(colBase + r) * Ktot + kb + off);
        }
        __syncthreads();

        #pragma unroll
        for (int kh = 0; kh < 2; ++kh) {
            int cidx = kh * 4 + quad;
            short8 af[4], bf4[4];
            #pragma unroll
            for (int i = 0; i < 4; ++i)
                af[i] = *(const short8*)&As[(wm + i * 16 + l15) * 64 + (cidx ^ sw7) * 8];
            #pragma unroll
            for (int j = 0; j < 4; ++j)
                bf4[j] = *(const short8*)&Bs[(wn + j * 16 + l15) * 64 + (cidx ^ sw7) * 8];
            // operand swap: acc[i][j][r] = C[wm+i*16+l15][wn+j*16+quad*4+r]
            #pragma unroll
            for (int i = 0; i < 4; ++i)
                #pragma unroll
                for (int j = 0; j < 4; ++j)
                    acc[i][j] = __builtin_amdgcn_mfma_f32_16x16x32_bf16(bf4[j], af[i], acc[i][j], 0, 0, 0);
        }
        __syncthreads();
    }

    // epilogue: per-wave 4KB LDS restage -> full-line bf16 stores
    ushort_t* lws = &As[wave * 2048];  // 8 waves x 2048 shorts = 32 KB = As
    #pragma unroll
    for (int p = 0; p < 2; ++p) {
        #pragma unroll
        for (int jj = 0; jj < 2; ++jj) {
            int j = 2 * p + jj;
            float4 bv = make_float4(0.f, 0.f, 0.f, 0.f);
            if (BIAS) bv = *(const float4*)(bias + colBase + wn + j * 16 + quad * 4);
            #pragma unroll
            for (int i = 0; i < 4; ++i) {
                uint2 pk;
                pk.x = (unsigned int)f2bf(acc[i][j][0] + bv.x) |
                       ((unsigned int)f2bf(acc[i][j][1] + bv.y) << 16);
                pk.y = (unsigned int)f2bf(acc[i][j][2] + bv.z) |
                       ((unsigned int)f2bf(acc[i][j][3] + bv.w) << 16);
                *(uint2*)&lws[(i * 16 + l15) * 32 + jj * 16 + quad * 4] = pk;
            }
        }
        __syncthreads();
        #pragma unroll
        for (int it = 0; it < 4; ++it) {
            int c = it * 64 + lane;
            int row = c >> 2, coff = (c & 3) * 8;
            int grow = rowBase + wm + row;
            if (grow < N) {
                uint4 v = *(const uint4*)&lws[row * 32 + coff];
                *(uint4*)(Cb + (size_t)grow * Wtot + colBase + wn + p * 32 + coff) = v;
            }
        }
        __syncthreads();
    }
}

// ---------------- BN stats (bf16 input) ------------------------------------
__global__ void colstats_b_kernel(const ushort_t* __restrict__ h, int N, int D,
                                  float* __restrict__ sum, float* __restrict__ sumsq) {
    int c2 = blockIdx.x * 128 + (threadIdx.x & 63) * 2;
    int rl = threadIdx.x >> 6;
    float s0 = 0.f, s20 = 0.f, s1 = 0.f, s21 = 0.f;
    int stride = gridDim.y * 4;
    for (int r = blockIdx.y * 4 + rl; r < N; r += stride) {
        unsigned int w = *(const unsigned int*)(h + (size_t)r * D + c2);
        float v0 = bflo(w), v1 = bfhi(w);
        s0 += v0; s20 += v0 * v0;
        s1 += v1; s21 += v1 * v1;
    }
    atomicAdd(&sum[c2 + 0], s0);
    atomicAdd(&sumsq[c2 + 0], s20);
    atomicAdd(&sum[c2 + 1], s1);
    atomicAdd(&sumsq[c2 + 1], s21);
}

// ---------------- BN apply (bf16 in) ---------------------------------------
__global__ void bn_relu_b2b_kernel(const ushort_t* __restrict__ h, ushort_t* __restrict__ hb,
                                   int N, int D,
                                   const float* __restrict__ sum, const float* __restrict__ sumsq,
                                   const float* __restrict__ g, const float* __restrict__ b) {
    size_t idx = (size_t)blockIdx.x * blockDim.x + threadIdx.x;
    size_t tot = (size_t)N * D / 2;
    if (idx >= tot) return;
    int cp = (int)(idx & (size_t)(D / 2 - 1));
    int c0 = cp * 2, c1 = c0 + 1;
    float m0 = sum[c0] / (float)N, m1 = sum[c1] / (float)N;
    float i0 = rsqrtf(sumsq[c0] / (float)N - m0 * m0 + EPS_BN);
    float i1 = rsqrtf(sumsq[c1] / (float)N - m1 * m1 + EPS_BN);
    unsigned int w = ((const unsigned int*)h)[idx];
    float v0 = g[c0] * (bflo(w) - m0) * i0 + b[c0];
    float v1 = g[c1] * (bfhi(w) - m1) * i1 + b[c1];
    v0 = v0 > 0.f ? v0 : 0.f;
    v1 = v1 > 0.f ? v1 : 0.f;
    ((unsigned int*)hb)[idx] = (unsigned int)f2bf(v0) | ((unsigned int)f2bf(v1) << 16);
}

__global__ void bn_relu_b2f_kernel(const ushort_t* __restrict__ h, float* __restrict__ hf,
                                   int N, int D,
                                   const float* __restrict__ sum, const float* __restrict__ sumsq,
                                   const float* __restrict__ g, const float* __restrict__ b) {
    size_t idx = (size_t)blockIdx.x * blockDim.x + threadIdx.x;
    size_t tot = (size_t)N * D / 2;
    if (idx >= tot) return;
    int cp = (int)(idx & (size_t)(D / 2 - 1));
    int c0 = cp * 2, c1 = c0 + 1;
    float m0 = sum[c0] / (float)N, m1 = sum[c1] / (float)N;
    float i0 = rsqrtf(sumsq[c0] / (float)N - m0 * m0 + EPS_BN);
    float i1 = rsqrtf(sumsq[c1] / (float)N - m1 * m1 + EPS_BN);
    unsigned int w = ((const unsigned int*)h)[idx];
    float v0 = g[c0] * (bflo(w) - m0) * i0 + b[c0];
    float v1 = g[c1] * (bfhi(w) - m1) * i1 + b[c1];
    float2 o;
    o.x = v0 > 0.f ? v0 : 0.f;
    o.y = v1 > 0.f ? v1 : 0.f;
    *(float2*)(hf + idx * 2) = o;
}

// ---------------------------------------------------------------------------
extern "C" void kernel_launch(void* const* d_in, const int* in_sizes, int n_in,
                              void* d_out, int out_size, void* d_ws, size_t ws_size,
                              hipStream_t stream) {
    const float* x     = (const float*)d_in[0];
    const int*   edges = (const int*)d_in[1];
    const float* Wl0 = (const float*)d_in[2];
    const float* bl0 = (const float*)d_in[3];
    const float* Wr0 = (const float*)d_in[4];
    const float* g0  = (const float*)d_in[5];
    const float* b0  = (const float*)d_in[6];
    const float* Wl1 = (const float*)d_in[7];
    const float* bl1 = (const float*)d_in[8];
    const float* Wr1 = (const float*)d_in[9];
    const float* g1  = (const float*)d_in[10];
    const float* b1  = (const float*)d_in[11];
    const float* Wl2 = (const float*)d_in[12];
    const float* bl2 = (const float*)d_in[13];
    const float* Wr2 = (const float*)d_in[14];
    const float* g2  = (const float*)d_in[15];
    const float* b2  = (const float*)d_in[16];

    const int D0 = 128, D1 = 512, D2 = 256, D3 = 128;
    const int n  = in_sizes[0] / D0;   // 50000
    const int ne = in_sizes[1] / 2;    // 800000
    const int NB = (n + 255) >> 8;     // 196 buckets

    // ---- workspace layout (zeroed block first -> one memset) ----
    char* base = (char*)d_ws;
    size_t off = 0;
    auto alloc = [&](size_t bytes) -> char* {
        char* p = base + off;
        off = (off + bytes + 255) & ~(size_t)255;
        return p;
    };
    int*      gcnt    = (int*)alloc(256 * 4);
    float*    stats   = (float*)alloc(6 * 512 * 4);
    size_t    zero_span = off;
    int*      bbase   = (int*)alloc(257 * 4);
    int*      bcur    = (int*)alloc(256 * 4);
    int*      packed  = (int*)alloc((size_t)ne * 4);
    int*      rowptr  = (int*)alloc((size_t)(n + 1) * 4);
    int*      csr_src = (int*)alloc((size_t)ne * 4);
    ushort_t* xb      = (ushort_t*)alloc((size_t)n * D0 * 2);
    ushort_t* mb      = (ushort_t*)alloc((size_t)n * 512 * 2);   // mean(L0) / PR(L1,L2)
    ushort_t* h1b     = (ushort_t*)alloc((size_t)n * D1 * 2);
    ushort_t* h2b     = (ushort_t*)alloc((size_t)n * D2 * 2);
    ushort_t* hpre    = (ushort_t*)alloc((size_t)n * 512 * 2);   // bf16 pre-BN
    ushort_t* WT0     = (ushort_t*)alloc((size_t)D1 * 2 * D0 * 2);
    ushort_t* WT1c    = (ushort_t*)alloc((size_t)(2 * D2) * D1 * 2);
    ushort_t* WT2c    = (ushort_t*)alloc((size_t)(2 * D3) * D2 * 2);
    float*    out     = (float*)d_out;
    (void)ws_size; (void)n_in; (void)out_size;

    hipMemsetAsync(base, 0, zero_span, stream);

    // ---- bucket-sort CSR build (edge format detected in-block) ----
    int ablk = (ne + EPB - 1) / EPB;
    bhist_kernel<<<ablk, 256, 0, stream>>>(edges, ne, gcnt);
    bscan_kernel<<<1, 256, 0, stream>>>(gcnt, NB, ne, bbase, bcur);
    bscatter_kernel<<<ablk, 256, 0, stream>>>(edges, ne, bcur, packed);
    bbuild_kernel<<<NB, 256, 0, stream>>>(packed, bbase, rowptr, csr_src, n);

    // ---- merged prep (x->bf16 + all weight transposes) ----
    const int nxb = (n * D0) / 256;               // 25000
    const int nb0 = (D1 * 2 * D0) / 256;          // 512
    const int nb1 = (2 * D2 * D1) / 256;          // 1024
    const int nb2 = (2 * D3 * D2) / 256;          // 256
    prep_all_kernel<<<nxb + nb0 + nb1 + nb2, 256, 0, stream>>>(
        x, xb, nxb, Wl0, Wr0, WT0, nb0, Wl1, Wr1, WT1c, nb1, Wl2, Wr2, WT2c);

    const int aggGrid = (n + 3) / 4;
    const int rowBlocks = (n + 255) / 256;   // 256-row GEMM tiles
    float* st0 = stats + 0 * 1024;
    float* st1 = stats + 1 * 1024;
    float* st2 = stats + 2 * 1024;

    // ---- layer 0: 128 -> 512 (aggregate-first: din < dout) ----
    aggregate_wave_kernel<2><<<aggGrid, 256, 0, stream>>>(xb, mb, rowptr, csr_src, n);
    gemm_glds_kernel<true, true><<<dim3(D1 / 128, rowBlocks), 512, 0, stream>>>(
        mb, xb, WT0, bl0, hpre, n, D0, 2 * D0, D1);
    colstats_b_kernel<<<dim3(D1 / 128, 128), 256, 0, stream>>>(hpre, n, D1, st0, st0 + 512);
    bn_relu_b2b_kernel<<<((size_t)n * D1 / 2 + 255) / 256, 256, 0, stream>>>(
        hpre, h1b, n, D1, st0, st0 + 512, g0, b0);

    // ---- layer 1: 512 -> 256 (project-first, fused [P|R]) ----
    gemm_glds_kernel<false, false><<<dim3(2 * D2 / 128, rowBlocks), 512, 0, stream>>>(
        h1b, nullptr, WT1c, nullptr, mb, n, D1, D1, 2 * D2);      // PR1 = h1 @ [Wl1|Wr1]
    aggregate_add_kernel<4><<<aggGrid, 256, 0, stream>>>(
        mb, bl1, hpre, rowptr, csr_src, n);                        // pre = mean(P)+R+bl1
    colstats_b_kernel<<<dim3(D2 / 128, 128), 256, 0, stream>>>(hpre, n, D2, st1, st1 + 512);
    bn_relu_b2b_kernel<<<((size_t)n * D2 / 2 + 255) / 256, 256, 0, stream>>>(
        hpre, h2b, n, D2, st1, st1 + 512, g1, b1);

    // ---- layer 2: 256 -> 128 (project-first, fused [P|R]) ----
    gemm_glds_kernel<false, false><<<dim3(2 * D3 / 128, rowBlocks), 512, 0, stream>>>(
        h2b, nullptr, WT2c, nullptr, mb, n, D2, D2, 2 * D3);      // PR2 = h2 @ [Wl2|Wr2]
    aggregate_add_kernel<2><<<aggGrid, 256, 0, stream>>>(
        mb, bl2, hpre, rowptr, csr_src, n);                        // pre = mean(P)+R+bl2
    colstats_b_kernel<<<dim3(D3 / 128, 128), 256, 0, stream>>>(hpre, n, D3, st2, st2 + 512);
    bn_relu_b2f_kernel<<<((size_t)n * D3 / 2 + 255) / 256, 256, 0, stream>>>(
        hpre, out, n, D3, st2, st2 + 512, g2, b2);
}